// Round 18
// baseline (546.806 us; speedup 1.0000x reference)
//
#include <hip/hip_runtime.h>

// MoEUT time-series decoder, round 26 = round-25 (546.4us) + fused prep.
// Round-25: barrier-free wave-LN WIN (-4.6us). All real kernels below the
// 40us counter cutoff -> remaining structure is dispatch boundaries.
// This round: the 5 serial weight-prep launches (qkv transpose, ow cvt,
// w1 transpose, w2 transpose, bias concat) fuse into ONE prep_all kernel
// (block-range dispatch, 22052 blocks, identical per-segment indexing).
// Everything else byte-identical to round 25.

#define LNUM 3
#define D 1024
#define H 16
#define HD 64
#define E 8
#define EH 256
#define B 2
#define S 1024
#define DIN 32
#define NOUT 8
#define EPS 1e-5f
#define TOK (B * S)

typedef __bf16 bf16x8 __attribute__((ext_vector_type(8)));
typedef __bf16 bf16x4 __attribute__((ext_vector_type(4)));
typedef float fx4 __attribute__((ext_vector_type(4)));

// ---------------- reductions ----------------
__device__ inline float block_reduce_sum256(float v, float* scratch) {
  int lane = threadIdx.x & 63, wv = threadIdx.x >> 6;
#pragma unroll
  for (int off = 32; off; off >>= 1) v += __shfl_down(v, off);
  __syncthreads();
  if (lane == 0) scratch[wv] = v;
  __syncthreads();
  return scratch[0] + scratch[1] + scratch[2] + scratch[3];
}

__device__ inline float wave_reduce_sum(float v) {
#pragma unroll
  for (int msk = 1; msk < 64; msk <<= 1) v += __shfl_xor(v, msk);
  return v;
}

// ------ LayerNorm -> bf16 (wave-per-token, barrier-free) -----------------
__global__ __launch_bounds__(256) void ln_bf_kernel(
    const float* __restrict__ in, const float* __restrict__ g,
    const float* __restrict__ bta, __bf16* __restrict__ outb) {
  int lane = threadIdx.x & 63, wv = threadIdx.x >> 6;
  int token = blockIdx.x * 4 + wv;
  const float* p = in + (size_t)token * D;
  float4 x[4];
  float s = 0.f, sq = 0.f;
#pragma unroll
  for (int j = 0; j < 4; j++) {
    x[j] = ((const float4*)p)[lane + j * 64];
    s += x[j].x + x[j].y + x[j].z + x[j].w;
    sq += x[j].x * x[j].x + x[j].y * x[j].y + x[j].z * x[j].z +
          x[j].w * x[j].w;
  }
  s = wave_reduce_sum(s);
  sq = wave_reduce_sum(sq);
  float mean = s * (1.f / D);
  float inv = rsqrtf(sq * (1.f / D) - mean * mean + EPS);
  __bf16* obp = outb + (size_t)token * D;
#pragma unroll
  for (int j = 0; j < 4; j++) {
    int d0 = (lane + j * 64) * 4;
    float4 gv = ((const float4*)g)[lane + j * 64];
    float4 bv = ((const float4*)bta)[lane + j * 64];
    float xv[4] = {x[j].x, x[j].y, x[j].z, x[j].w};
    float gg[4] = {gv.x, gv.y, gv.z, gv.w};
    float bb[4] = {bv.x, bv.y, bv.z, bv.w};
    bf16x4 o;
#pragma unroll
    for (int i = 0; i < 4; i++)
      o[i] = (__bf16)((xv[i] - mean) * inv * gg[i] + bb[i]);
    *(bf16x4*)(obp + d0) = o;
  }
}

// ---- LayerNorm + sigmoid gate top-2 (wave-per-token, barrier-free) -----
__global__ __launch_bounds__(256) void ln_gate_kernel(
    const float* __restrict__ in, const float* __restrict__ g,
    const float* __restrict__ bta, const float* __restrict__ selw,
    __bf16* __restrict__ outb, float* __restrict__ gm) {
  int lane = threadIdx.x & 63, wv = threadIdx.x >> 6;
  int token = blockIdx.x * 4 + wv;
  const float* p = in + (size_t)token * D;
  float4 x[4];
  float s = 0.f, sq = 0.f;
#pragma unroll
  for (int j = 0; j < 4; j++) {
    x[j] = ((const float4*)p)[lane + j * 64];
    s += x[j].x + x[j].y + x[j].z + x[j].w;
    sq += x[j].x * x[j].x + x[j].y * x[j].y + x[j].z * x[j].z +
          x[j].w * x[j].w;
  }
  s = wave_reduce_sum(s);
  sq = wave_reduce_sum(sq);
  float mean = s * (1.f / D);
  float inv = rsqrtf(sq * (1.f / D) - mean * mean + EPS);
  __bf16* obp = outb + (size_t)token * D;
  float ge[E];
#pragma unroll
  for (int e = 0; e < E; e++) ge[e] = 0.f;
#pragma unroll
  for (int j = 0; j < 4; j++) {
    int v4 = lane + j * 64;
    int d0 = v4 * 4;
    float4 gv = ((const float4*)g)[v4];
    float4 bv = ((const float4*)bta)[v4];
    float xv[4] = {x[j].x, x[j].y, x[j].z, x[j].w};
    float gg[4] = {gv.x, gv.y, gv.z, gv.w};
    float bb[4] = {bv.x, bv.y, bv.z, bv.w};
    bf16x4 o;
    const float4* sw4 = (const float4*)(selw + (size_t)d0 * E);
#pragma unroll
    for (int i = 0; i < 4; i++) {
      float y = (xv[i] - mean) * inv * gg[i] + bb[i];
      o[i] = (__bf16)y;
      float4 a = sw4[i * 2], b2 = sw4[i * 2 + 1];
      ge[0] += y * a.x;
      ge[1] += y * a.y;
      ge[2] += y * a.z;
      ge[3] += y * a.w;
      ge[4] += y * b2.x;
      ge[5] += y * b2.y;
      ge[6] += y * b2.z;
      ge[7] += y * b2.w;
    }
    *(bf16x4*)(obp + d0) = o;
  }
#pragma unroll
  for (int e = 0; e < E; e++) ge[e] = wave_reduce_sum(ge[e]);
  if (lane == 0) {
    float gg[E];
#pragma unroll
    for (int e = 0; e < E; e++) gg[e] = 1.f / (1.f + __expf(-ge[e]));
    int i0 = 0;
    for (int e = 1; e < E; e++)
      if (gg[e] > gg[i0]) i0 = e;
    int i1 = -1;
    for (int e = 0; e < E; e++) {
      if (e == i0) continue;
      if (i1 < 0 || gg[e] > gg[i1]) i1 = e;
    }
    float mm[E];
    for (int e = 0; e < E; e++) mm[e] = 0.f;
    mm[i0] = gg[i0];
    mm[i1] = gg[i1];
    for (int e = 0; e < E; e++) gm[(size_t)token * E + e] = mm[e];
  }
}

// ---------------- fp32 tiled GEMM (input projection, K=32) ----------
#define BM 64
#define BKT 16
__global__ __launch_bounds__(256) void gemm_kernel(
    const float* __restrict__ A, const float* __restrict__ Bw,
    const float* __restrict__ bias, float* __restrict__ C, int M, int N,
    int Kd) {
  __shared__ float As[BKT][BM + 1];
  __shared__ float Bs[BKT][BM + 1];
  int bm = blockIdx.y * BM, bn = blockIdx.x * BM;
  int tid = threadIdx.x;
  int tx = tid & 15, ty = tid >> 4;
  float acc[4][4] = {};
  for (int k0 = 0; k0 < Kd; k0 += BKT) {
#pragma unroll
    for (int j = 0; j < 4; j++) {
      int i = tid + j * 256;
      int r = i >> 4, c = i & 15;
      As[c][r] = A[(size_t)(bm + r) * Kd + k0 + c];
    }
#pragma unroll
    for (int j = 0; j < 4; j++) {
      int i = tid + j * 256;
      int n = i >> 4, c = i & 15;
      Bs[c][n] = Bw[(size_t)(bn + n) * Kd + k0 + c];
    }
    __syncthreads();
#pragma unroll
    for (int kk = 0; kk < BKT; kk++) {
      float a[4], bb[4];
#pragma unroll
      for (int i2 = 0; i2 < 4; i2++) a[i2] = As[kk][ty * 4 + i2];
#pragma unroll
      for (int i2 = 0; i2 < 4; i2++) bb[i2] = Bs[kk][tx * 4 + i2];
#pragma unroll
      for (int i2 = 0; i2 < 4; i2++)
#pragma unroll
        for (int j2 = 0; j2 < 4; j2++) acc[i2][j2] += a[i2] * bb[j2];
    }
    __syncthreads();
  }
#pragma unroll
  for (int i2 = 0; i2 < 4; i2++) {
    int row = bm + ty * 4 + i2;
#pragma unroll
    for (int j2 = 0; j2 < 4; j2++) {
      int col = bn + tx * 4 + j2;
      C[(size_t)row * N + col] = acc[i2][j2] + bias[col];
    }
  }
}

// ------- bf16 MFMA GEMM, 64xBN, templated BK, dbuf, XOR swizzle ---------
template <int NI, int BKQ>
__global__ __launch_bounds__(256) void mfma_gemm(
    const __bf16* __restrict__ A, int lda, const __bf16* __restrict__ Bt,
    const float* __restrict__ bias, float* __restrict__ C,
    __bf16* __restrict__ Cbf, int ldc, __bf16* __restrict__ vT,
    const float* __restrict__ gateScale, int K, int accum, int relu,
    int rope) {
  constexpr int BN = NI * 32;
  constexpr int CH = BKQ / 8;    // k-chunks (16B) per row
  constexpr int KKN = BKQ / 32;  // MFMA k-steps per iter
  constexpr int A_ELE = 64 * BKQ;
  constexpr int B_ELE = BN * BKQ;
  constexpr int STAGE_ELEMS = 2 * A_ELE + 2 * B_ELE;
  constexpr int TRANS_ELEMS = 128 * 66;  // vT transpose tile (NI=4 only)
  constexpr int SMEM_ELEMS =
      (TRANS_ELEMS > STAGE_ELEMS) ? TRANS_ELEMS : STAGE_ELEMS;
  __shared__ __bf16 smem[SMEM_ELEMS];
  __bf16* Asb = smem;              // [2][64*BKQ]
  __bf16* Bsb = smem + 2 * A_ELE;  // [2][BN*BKQ]
  // ---- T1: XCD-aware chunked remap (row-major chunks; nwg % 8 == 0) ----
  int nwg = gridDim.x * gridDim.y;
  int bid = blockIdx.y * gridDim.x + blockIdx.x;
  int t = (bid & 7) * (nwg >> 3) + (bid >> 3);
  int bxx = t % gridDim.x, byy = t / gridDim.x;
  int bm = byy * 64, bn = bxx * BN;
  int tid = threadIdx.x, lane = tid & 63, wv = tid >> 6;
  int wr = wv >> 1, wc = wv & 1;
  int half = lane >> 4, mrow = lane & 15;
  const __bf16* Ab = A + (size_t)bm * lda;
  const __bf16* Bb = Bt + (size_t)bn * K;
  fx4 acc[2][NI] = {};

  int abase[2], bbase[NI];
#pragma unroll
  for (int i = 0; i < 2; i++) abase[i] = wr * 32 + i * 16 + mrow;
#pragma unroll
  for (int j = 0; j < NI; j++) bbase[j] = wc * (NI * 16) + j * 16 + mrow;

  auto stage = [&](int buf, int k0) {
#pragma unroll
    for (int it = 0; it < (64 * CH) / 256; it++) {
      int c = tid + it * 256;
      int row = c / CH, g = (c % CH) ^ (row & (CH - 1));
      __builtin_amdgcn_global_load_lds(
          (const __attribute__((address_space(1))) void*)(Ab +
                                                          (size_t)row * lda +
                                                          k0 + g * 8),
          (__attribute__((address_space(3))) void*)(&Asb[buf * A_ELE + c * 8]),
          16, 0, 0);
    }
#pragma unroll
    for (int it = 0; it < (BN * CH) / 256; it++) {
      int c = tid + it * 256;
      int row = c / CH, g = (c % CH) ^ (row & (CH - 1));
      __builtin_amdgcn_global_load_lds(
          (const __attribute__((address_space(1))) void*)(Bb + (size_t)row * K +
                                                          k0 + g * 8),
          (__attribute__((address_space(3))) void*)(&Bsb[buf * B_ELE + c * 8]),
          16, 0, 0);
    }
  };
  stage(0, 0);
  for (int k0 = 0; k0 < K; k0 += BKQ) {
    int cur = (k0 / BKQ) & 1;
    __syncthreads();
    if (k0 + BKQ < K) stage(cur ^ 1, k0 + BKQ);
    bf16x8 af[2][KKN], bfr[NI][KKN];
#pragma unroll
    for (int i = 0; i < 2; i++) {
      int r = abase[i];
#pragma unroll
      for (int kk = 0; kk < KKN; kk++)
        af[i][kk] = *(const bf16x8*)(&Asb[cur * A_ELE + r * BKQ +
                                          (((kk * 4 + half) ^ (r & (CH - 1)))
                                           << 3)]);
    }
#pragma unroll
    for (int j = 0; j < NI; j++) {
      int r = bbase[j];
#pragma unroll
      for (int kk = 0; kk < KKN; kk++)
        bfr[j][kk] = *(const bf16x8*)(&Bsb[cur * B_ELE + r * BKQ +
                                           (((kk * 4 + half) ^ (r & (CH - 1)))
                                            << 3)]);
    }
#pragma unroll
    for (int kk = 0; kk < KKN; kk++)
#pragma unroll
      for (int i = 0; i < 2; i++)
#pragma unroll
        for (int j = 0; j < NI; j++)
          acc[i][j] = __builtin_amdgcn_mfma_f32_16x16x32_bf16(
              af[i][kk], bfr[j][kk], acc[i][j], 0, 0, 0);
  }
  if (vT && bn >= 2048) {
    // LDS-staged transpose: tile [d_local 0..127][tok_local 0..63], pad 66.
    __syncthreads();  // all waves done reading staging LDS
    __bf16* tb = smem;
#pragma unroll
    for (int i = 0; i < 2; i++) {
      int tl0 = wr * 32 + i * 16 + half * 4;
#pragma unroll
      for (int j = 0; j < NI; j++) {
        int dl = wc * (NI * 16) + j * 16 + mrow;
        float bb = bias ? bias[bn + dl] : 0.f;
#pragma unroll
        for (int r = 0; r < 4; r++)
          tb[dl * 66 + tl0 + r] = (__bf16)(acc[i][j][r] + bb);
      }
    }
    __syncthreads();
    // write out: 128 d-rows x 64 tokens; 8 lanes x bf16x8 = 128B full line
#pragma unroll
    for (int it = 0; it < 4; it++) {
      int idx = tid + it * 256;
      int dl = idx >> 3, c8 = idx & 7;
      bf16x8 v = *(const bf16x8*)(tb + dl * 66 + c8 * 8);
      *(bf16x8*)(vT + (size_t)(bn - 2048 + dl) * TOK + bm + c8 * 8) = v;
    }
    return;
  }
#pragma unroll
  for (int i = 0; i < 2; i++) {
#pragma unroll
    for (int r = 0; r < 4; r++) {
      int row = bm + wr * 32 + i * 16 + half * 4 + r;
      float vv[NI];
#pragma unroll
      for (int j = 0; j < NI; j++) {
        int col = bn + wc * (NI * 16) + j * 16 + mrow;
        float val = acc[i][j][r];
        if (bias) val += bias[col];
        if (relu) val = fmaxf(val, 0.f);
        if (gateScale) val *= gateScale[(size_t)row * E + (col >> 8)];
        vv[j] = val;
      }
      if (rope && NI == 4) {
        int spos = row & (S - 1);
#pragma unroll
        for (int jj = 0; jj < 2; jj++) {
          int hd = jj * 16 + mrow;  // 0..31
          float invf = exp2f(hd * -0.4152410118609825f);
          float ang = (float)spos * invf;
          float sn, cs;
          __sincosf(ang, &sn, &cs);
          float a0 = vv[jj], a1 = vv[jj + 2];
          vv[jj] = a0 * cs - a1 * sn;
          vv[jj + 2] = a1 * cs + a0 * sn;
        }
      }
#pragma unroll
      for (int j = 0; j < NI; j++) {
        int col = bn + wc * (NI * 16) + j * 16 + mrow;
        size_t addr = (size_t)row * ldc + col;
        if (Cbf)
          Cbf[addr] = (__bf16)vv[j];
        else if (accum)
          C[addr] += vv[j];
        else
          C[addr] = vv[j];
      }
    }
  }
}

// ---- fused weight prep: qkv/w1/w2 transposes + ow cvt + bias concat ----
// One launch, block-range dispatch:
// [0,9216): qkv  (z = w*LNUM+l, 32x32 tiles over DxD)
// [9216,15360): w1 (z = l*E+e, 8x32 tiles: c over EH, r over D)
// [15360,21504): w2 (z = l*E+e, 32x8 tiles: c over D, r over EH)
// [21504,22016): ow f32->bf16 grid-stride cvt (512 blocks)
// [22016,22052): qkv bias concat (36 blocks)
#define PREP_BLOCKS 22052
__global__ __launch_bounds__(256) void prep_all(
    const float* __restrict__ qw, const float* __restrict__ kw,
    const float* __restrict__ vw, __bf16* __restrict__ qkvt,
    const float* __restrict__ w1, __bf16* __restrict__ w1t,
    const float* __restrict__ w2, __bf16* __restrict__ w2t,
    const float* __restrict__ ow, __bf16* __restrict__ owt,
    const float* __restrict__ qb, const float* __restrict__ kb,
    const float* __restrict__ vb, float* __restrict__ qkvbias) {
  __shared__ float t[32][33];
  int bid = blockIdx.x;
  int tid = threadIdx.x;
  int tx = tid & 31, ty = tid >> 5;
  if (bid < 9216) {
    int z = bid >> 10, rem = bid & 1023;
    int by = rem >> 5, bx = rem & 31;
    int w = z / LNUM, l = z % LNUM;
    const float* src = (w == 0 ? qw : (w == 1 ? kw : vw)) + (size_t)l * D * D;
    __bf16* d = qkvt + (size_t)l * 3 * D * D + (size_t)w * D * D;
    int r0 = by * 32, c0 = bx * 32;
#pragma unroll
    for (int i = 0; i < 4; i++)
      t[ty + i * 8][tx] = src[(size_t)(r0 + ty + i * 8) * D + c0 + tx];
    __syncthreads();
#pragma unroll
    for (int i = 0; i < 4; i++)
      d[(size_t)(c0 + ty + i * 8) * D + r0 + tx] = (__bf16)t[tx][ty + i * 8];
  } else if (bid < 15360) {
    int b2 = bid - 9216;
    int z = b2 >> 8, rem = b2 & 255;
    int by = rem >> 3, bx = rem & 7;  // r over D (32), c over EH (8)
    const float* src = w1 + (size_t)z * D * EH;
    __bf16* d = w1t + (size_t)z * EH * D;
    int r0 = by * 32, c0 = bx * 32;
#pragma unroll
    for (int i = 0; i < 4; i++)
      t[ty + i * 8][tx] = src[(size_t)(r0 + ty + i * 8) * EH + c0 + tx];
    __syncthreads();
#pragma unroll
    for (int i = 0; i < 4; i++)
      d[(size_t)(c0 + ty + i * 8) * D + r0 + tx] = (__bf16)t[tx][ty + i * 8];
  } else if (bid < 21504) {
    int b2 = bid - 15360;
    int z = b2 >> 8, rem = b2 & 255;
    int by = rem >> 5, bx = rem & 31;  // r over EH (8), c over D (32)
    int l = z / E, e = z % E;
    const float* src = w2 + (size_t)z * EH * D;
    __bf16* d = w2t + (size_t)l * D * E * EH + (size_t)e * EH;
    int r0 = by * 32, c0 = bx * 32;
#pragma unroll
    for (int i = 0; i < 4; i++)
      t[ty + i * 8][tx] = src[(size_t)(r0 + ty + i * 8) * D + c0 + tx];
    __syncthreads();
#pragma unroll
    for (int i = 0; i < 4; i++)
      d[(size_t)(c0 + ty + i * 8) * (E * EH) + r0 + tx] =
          (__bf16)t[tx][ty + i * 8];
  } else if (bid < 22016) {
    int b2 = bid - 21504;
    int n = LNUM * D * D;
    for (int i = b2 * 256 + tid; i < n; i += 512 * 256)
      owt[i] = (__bf16)ow[i];
  } else {
    int b2 = bid - 22016;
    int i = b2 * 256 + tid;
    if (i < LNUM * 3 * D) {
      int l = i / (3 * D), r = i % (3 * D);
      int w = r / D, dd = r % D;
      const float* src = w == 0 ? qb : (w == 1 ? kb : vb);
      qkvbias[i] = src[l * D + dd];
    }
  }
}

// ---------------- dbuf async-staged flash attention ----------------------
// Proven KVBLK=64 config: no-max softmax + deferred l-reduction; T1 remap.
#define P_LD 72
__global__ __launch_bounds__(256) void attn_dbuf(
    const __bf16* __restrict__ qk, const __bf16* __restrict__ vT,
    __bf16* __restrict__ obf) {
  __shared__ __bf16 Kt[2][64 * 64];    // 16 KB
  __shared__ __bf16 Vt[2][64 * 64];    // 16 KB
  __shared__ __bf16 Pb[4][16 * P_LD];  // 9 KB
  // ---- T1: XCD-aware chunked remap (nwg = 512, chunk = 64 = 4 hb) ----
  int nwg = gridDim.x * gridDim.y;
  int bid = blockIdx.y * gridDim.x + blockIdx.x;
  int t = (bid & 7) * (nwg >> 3) + (bid >> 3);
  int hb = t / gridDim.y;
  int q0 = (t % gridDim.y) * 64;
  int hh = hb >> 1, b = hb & 1;
  int tid = threadIdx.x, lane = tid & 63, wv = tid >> 6;
  int col = lane & 15, half = lane >> 4;
  const float scale = 0.125f;  // HD^-0.5
  __bf16* P = &Pb[wv][0];

  const __bf16* qp = qk + (size_t)(b * S + q0 + wv * 16 + col) * 2048 + hh * HD;
  bf16x8 qf0 = *(const bf16x8*)(qp + half * 8);
  bf16x8 qf1 = *(const bf16x8*)(qp + 32 + half * 8);
  const __bf16* kbase = qk + (size_t)(b * S) * 2048 + 1024 + hh * HD;
  const __bf16* vbase = vT + (size_t)(hh * HD) * TOK + b * S;

  int srow = tid >> 3, sslot = tid & 7;
  int sg = sslot ^ (srow & 7);
  int srow2 = (tid + 256) >> 3, sslot2 = tid & 7;
  int sg2 = sslot2 ^ (srow2 & 7);

  auto stage = [&](int buf, int t0) {
    __builtin_amdgcn_global_load_lds(
        (const __attribute__((address_space(1))) void*)(kbase +
                                                        (size_t)(t0 + srow) *
                                                            2048 +
                                                        sg * 8),
        (__attribute__((address_space(3))) void*)(&Kt[buf][tid * 8]), 16, 0, 0);
    __builtin_amdgcn_global_load_lds(
        (const __attribute__((address_space(1))) void*)(kbase +
                                                        (size_t)(t0 + srow2) *
                                                            2048 +
                                                        sg2 * 8),
        (__attribute__((address_space(3))) void*)(&Kt[buf][(tid + 256) * 8]),
        16, 0, 0);
    __builtin_amdgcn_global_load_lds(
        (const __attribute__((address_space(1))) void*)(vbase +
                                                        (size_t)srow * TOK +
                                                        t0 + sg * 8),
        (__attribute__((address_space(3))) void*)(&Vt[buf][tid * 8]), 16, 0, 0);
    __builtin_amdgcn_global_load_lds(
        (const __attribute__((address_space(1))) void*)(vbase +
                                                        (size_t)srow2 * TOK +
                                                        t0 + sg2 * 8),
        (__attribute__((address_space(3))) void*)(&Vt[buf][(tid + 256) * 8]),
        16, 0, 0);
  };

  fx4 Oacc[4] = {};
  float lpart[4] = {0.f, 0.f, 0.f, 0.f};

  stage(0, 0);
  for (int t0 = 0; t0 < S; t0 += 64) {
    int cur = (t0 >> 6) & 1;
    __syncthreads();
    if (t0 + 64 < S) stage(cur ^ 1, t0 + 64);
    // S = Q @ K^T
    fx4 sacc[4] = {};
#pragma unroll
    for (int n = 0; n < 4; n++) {
      int rowk = n * 16 + col;
      const __bf16* kp = &Kt[cur][rowk * 64];
      bf16x8 b0 = *(const bf16x8*)(kp + ((half ^ (rowk & 7)) << 3));
      bf16x8 b1 = *(const bf16x8*)(kp + (((4 + half) ^ (rowk & 7)) << 3));
      sacc[n] =
          __builtin_amdgcn_mfma_f32_16x16x32_bf16(qf0, b0, sacc[n], 0, 0, 0);
      sacc[n] =
          __builtin_amdgcn_mfma_f32_16x16x32_bf16(qf1, b1, sacc[n], 0, 0, 0);
    }
    // no-max softmax numerator
#pragma unroll
    for (int r = 0; r < 4; r++) {
      int prow = (half * 4 + r) * P_LD;
#pragma unroll
      for (int n = 0; n < 4; n++) {
        float p = __expf(sacc[n][r] * scale);
        lpart[r] += p;
        P[prow + n * 16 + col] = (__bf16)p;
      }
    }
    // O += P @ V
#pragma unroll
    for (int k0 = 0; k0 < 2; k0++) {
      bf16x8 af = *(const bf16x8*)(P + col * P_LD + k0 * 32 + half * 8);
#pragma unroll
      for (int n = 0; n < 4; n++) {
        int rowd = n * 16 + col;
        int g = k0 * 4 + half;
        bf16x8 bv =
            *(const bf16x8*)(&Vt[cur][rowd * 64 + ((g ^ (rowd & 7)) << 3)]);
        Oacc[n] =
            __builtin_amdgcn_mfma_f32_16x16x32_bf16(af, bv, Oacc[n], 0, 0, 0);
      }
    }
  }
#pragma unroll
  for (int r = 0; r < 4; r++) {
    float l = lpart[r];
#pragma unroll
    for (int msk = 1; msk < 16; msk <<= 1) l += __shfl_xor(l, msk);
    float inv = 1.f / l;
    int row = q0 + wv * 16 + half * 4 + r;
    __bf16* op = obf + (size_t)(b * S + row) * D + hh * HD;
#pragma unroll
    for (int n = 0; n < 4; n++) op[n * 16 + col] = (__bf16)(Oacc[n][r] * inv);
  }
}

// ---------------- final head: last token only ----------------
__global__ __launch_bounds__(256) void final_kernel(
    const float* __restrict__ h, const float* __restrict__ tg,
    const float* __restrict__ tb, const float* __restrict__ dg,
    const float* __restrict__ db, const float* __restrict__ ow,
    const float* __restrict__ ob, float* __restrict__ out) {
  int b = blockIdx.x;
  int tid = threadIdx.x;
  __shared__ float scratch[4];
  __shared__ float yf[D];
  const float* p = h + ((size_t)(b * S + (S - 1))) * D;
  float x[4];
  float s = 0.f, sq = 0.f;
#pragma unroll
  for (int i = 0; i < 4; i++) {
    x[i] = p[tid + i * 256];
    s += x[i];
    sq += x[i] * x[i];
  }
  s = block_reduce_sum256(s, scratch);
  sq = block_reduce_sum256(sq, scratch);
  float mean = s * (1.f / D);
  float inv = rsqrtf(sq * (1.f / D) - mean * mean + EPS);
  float y[4];
  s = 0.f;
  sq = 0.f;
#pragma unroll
  for (int i = 0; i < 4; i++) {
    int d = tid + i * 256;
    y[i] = (x[i] - mean) * inv * tg[d] + tb[d];
    s += y[i];
    sq += y[i] * y[i];
  }
  s = block_reduce_sum256(s, scratch);
  sq = block_reduce_sum256(sq, scratch);
  float mean2 = s * (1.f / D);
  float inv2 = rsqrtf(sq * (1.f / D) - mean2 * mean2 + EPS);
#pragma unroll
  for (int i = 0; i < 4; i++) {
    int d = tid + i * 256;
    yf[d] = (y[i] - mean2) * inv2 * dg[d] + db[d];
  }
  __syncthreads();
  for (int oo = 0; oo < NOUT; oo++) {
    float part = 0.f;
    for (int d = tid; d < D; d += 256) part += yf[d] * ow[(size_t)oo * D + d];
    part = block_reduce_sum256(part, scratch);
    if (tid == 0) out[b * NOUT + oo] = part + ob[oo];
  }
}

extern "C" void kernel_launch(void* const* d_in, const int* in_sizes, int n_in,
                              void* d_out, int out_size, void* d_ws,
                              size_t ws_size, hipStream_t stream) {
  const float* x = (const float*)d_in[0];
  const float* ln1_g = (const float*)d_in[1];
  const float* ln1_b = (const float*)d_in[2];
  const float* qw = (const float*)d_in[3];
  const float* qb_ = (const float*)d_in[4];
  const float* kw = (const float*)d_in[5];
  const float* kb_ = (const float*)d_in[6];
  const float* vw = (const float*)d_in[7];
  const float* vb_ = (const float*)d_in[8];
  const float* ow = (const float*)d_in[9];
  const float* ob = (const float*)d_in[10];
  const float* ln2_g = (const float*)d_in[11];
  const float* ln2_b = (const float*)d_in[12];
  const float* selw = (const float*)d_in[13];
  const float* w1 = (const float*)d_in[14];
  const float* w2 = (const float*)d_in[15];
  const float* lntg = (const float*)d_in[16];
  const float* lntb = (const float*)d_in[17];
  const float* lndg = (const float*)d_in[18];
  const float* lndb = (const float*)d_in[19];
  const float* inw = (const float*)d_in[20];
  const float* inb = (const float*)d_in[21];
  const float* outw = (const float*)d_in[22];
  const float* outb = (const float*)d_in[23];
  float* out = (float*)d_out;

  // ---- workspace layout (~76 MB) ----
  float* h = (float*)d_ws;                          // TOK*D f32
  float* gm = h + (size_t)TOK * D;                  // TOK*E
  float* qkvbias = gm + (size_t)TOK * E;            // L*3*D
  __bf16* xnb = (__bf16*)(qkvbias + LNUM * 3 * D);  // TOK*D
  __bf16* qkbf = xnb + (size_t)TOK * D;             // TOK*2048 (q|k)
  __bf16* vTb = qkbf + (size_t)TOK * 2048;          // D*TOK (v transposed)
  __bf16* obf = vTb + (size_t)D * TOK;              // TOK*D
  __bf16* qkvt = obf + (size_t)TOK * D;             // L*3*D*D
  __bf16* owt = qkvt + (size_t)LNUM * 3 * D * D;    // L*D*D
  __bf16* w1t = owt + (size_t)LNUM * D * D;         // L*E*EH*D
  __bf16* w2t = w1t + (size_t)LNUM * E * EH * D;    // L*D*E*EH
  __bf16* midb = qkbf;  // alias: q|k dead after attn; [TOK][2048]

  // ---- weight prep: ONE launch ----
  prep_all<<<PREP_BLOCKS, 256, 0, stream>>>(qw, kw, vw, qkvt, w1, w1t, w2, w2t,
                                            ow, owt, qb_, kb_, vb_, qkvbias);

  gemm_kernel<<<dim3(D / 64, TOK / 64), 256, 0, stream>>>(x, inw, inb, h, TOK,
                                                          D, DIN);
  for (int l = 0; l < LNUM; l++) {
    ln_bf_kernel<<<TOK / 4, 256, 0, stream>>>(h, ln1_g + l * D, ln1_b + l * D,
                                              xnb);
    // qkv folded: N=3072; q,k -> qkbf[token][2048] (+RoPE), v -> vT[d][token]
    mfma_gemm<4, 64><<<dim3(3072 / 128, TOK / 64), 256, 0, stream>>>(
        xnb, D, qkvt + (size_t)l * 3 * D * D, qkvbias + l * 3 * D, nullptr,
        qkbf, 2048, vTb, nullptr, D, 0, 0, 1);
    attn_dbuf<<<dim3(H * B, S / 64), 256, 0, stream>>>(qkbf, vTb, obf);
    // h += o @ ow^T + ob  (BK=128 -> 8 K-iters)
    mfma_gemm<2, 128><<<dim3(D / 64, TOK / 64), 256, 0, stream>>>(
        obf, D, owt + (size_t)l * D * D, ob + l * D, h, nullptr, D, nullptr,
        nullptr, D, 1, 0, 0);
    ln_gate_kernel<<<TOK / 4, 256, 0, stream>>>(h, ln2_g + l * D, ln2_b + l * D,
                                                selw + (size_t)l * D * E, xnb,
                                                gm);
    // w1 folded: mid[t][e*EH+eh] = relu(xn @ w1cat) * gate[t][e]
    mfma_gemm<4, 64><<<dim3(2048 / 128, TOK / 64), 256, 0, stream>>>(
        xnb, D, w1t + (size_t)l * E * EH * D, nullptr, nullptr, midb, 2048,
        nullptr, gm, D, 0, 1, 0);
    // h += mid @ w2stacked (K=2048, BK=128 -> 16 K-iters)
    mfma_gemm<2, 128><<<dim3(D / 64, TOK / 64), 256, 0, stream>>>(
        midb, 2048, w2t + (size_t)l * D * E * EH, nullptr, h, nullptr, D,
        nullptr, nullptr, 2048, 1, 0, 0);
  }
  final_kernel<<<B, 256, 0, stream>>>(h, lntg, lntb, lndg, lndb, outw, outb,
                                      out);
}

// Round 19
// 531.885 us; speedup vs baseline: 1.0281x; 1.0281x over previous
//
#include <hip/hip_runtime.h>

// MoEUT time-series decoder, round 27 = round-26 + vectorized prep_all.
// Round-26: prep fusion neutral BUT exposed prep_all as top dispatch:
// 43us, 2.3 TB/s (29% peak), 100MB moved with no amplification ->
// classic G13 scalar-access kernel (4B f32 loads, 2B bf16 stores).
// Fix: float4 reads (16B/lane) + bf16x4 writes (8B/lane) in all three
// transpose segments (LDS staging scalar, pad-33 = <=2-way banks) and
// float4->bf16x4 ow cvt. Same tiles/grids/ranges; all other kernels
// byte-identical to round 25/26 (546.4us best).

#define LNUM 3
#define D 1024
#define H 16
#define HD 64
#define E 8
#define EH 256
#define B 2
#define S 1024
#define DIN 32
#define NOUT 8
#define EPS 1e-5f
#define TOK (B * S)

typedef __bf16 bf16x8 __attribute__((ext_vector_type(8)));
typedef __bf16 bf16x4 __attribute__((ext_vector_type(4)));
typedef float fx4 __attribute__((ext_vector_type(4)));

// ---------------- reductions ----------------
__device__ inline float block_reduce_sum256(float v, float* scratch) {
  int lane = threadIdx.x & 63, wv = threadIdx.x >> 6;
#pragma unroll
  for (int off = 32; off; off >>= 1) v += __shfl_down(v, off);
  __syncthreads();
  if (lane == 0) scratch[wv] = v;
  __syncthreads();
  return scratch[0] + scratch[1] + scratch[2] + scratch[3];
}

__device__ inline float wave_reduce_sum(float v) {
#pragma unroll
  for (int msk = 1; msk < 64; msk <<= 1) v += __shfl_xor(v, msk);
  return v;
}

// ------ LayerNorm -> bf16 (wave-per-token, barrier-free) -----------------
__global__ __launch_bounds__(256) void ln_bf_kernel(
    const float* __restrict__ in, const float* __restrict__ g,
    const float* __restrict__ bta, __bf16* __restrict__ outb) {
  int lane = threadIdx.x & 63, wv = threadIdx.x >> 6;
  int token = blockIdx.x * 4 + wv;
  const float* p = in + (size_t)token * D;
  float4 x[4];
  float s = 0.f, sq = 0.f;
#pragma unroll
  for (int j = 0; j < 4; j++) {
    x[j] = ((const float4*)p)[lane + j * 64];
    s += x[j].x + x[j].y + x[j].z + x[j].w;
    sq += x[j].x * x[j].x + x[j].y * x[j].y + x[j].z * x[j].z +
          x[j].w * x[j].w;
  }
  s = wave_reduce_sum(s);
  sq = wave_reduce_sum(sq);
  float mean = s * (1.f / D);
  float inv = rsqrtf(sq * (1.f / D) - mean * mean + EPS);
  __bf16* obp = outb + (size_t)token * D;
#pragma unroll
  for (int j = 0; j < 4; j++) {
    int d0 = (lane + j * 64) * 4;
    float4 gv = ((const float4*)g)[lane + j * 64];
    float4 bv = ((const float4*)bta)[lane + j * 64];
    float xv[4] = {x[j].x, x[j].y, x[j].z, x[j].w};
    float gg[4] = {gv.x, gv.y, gv.z, gv.w};
    float bb[4] = {bv.x, bv.y, bv.z, bv.w};
    bf16x4 o;
#pragma unroll
    for (int i = 0; i < 4; i++)
      o[i] = (__bf16)((xv[i] - mean) * inv * gg[i] + bb[i]);
    *(bf16x4*)(obp + d0) = o;
  }
}

// ---- LayerNorm + sigmoid gate top-2 (wave-per-token, barrier-free) -----
__global__ __launch_bounds__(256) void ln_gate_kernel(
    const float* __restrict__ in, const float* __restrict__ g,
    const float* __restrict__ bta, const float* __restrict__ selw,
    __bf16* __restrict__ outb, float* __restrict__ gm) {
  int lane = threadIdx.x & 63, wv = threadIdx.x >> 6;
  int token = blockIdx.x * 4 + wv;
  const float* p = in + (size_t)token * D;
  float4 x[4];
  float s = 0.f, sq = 0.f;
#pragma unroll
  for (int j = 0; j < 4; j++) {
    x[j] = ((const float4*)p)[lane + j * 64];
    s += x[j].x + x[j].y + x[j].z + x[j].w;
    sq += x[j].x * x[j].x + x[j].y * x[j].y + x[j].z * x[j].z +
          x[j].w * x[j].w;
  }
  s = wave_reduce_sum(s);
  sq = wave_reduce_sum(sq);
  float mean = s * (1.f / D);
  float inv = rsqrtf(sq * (1.f / D) - mean * mean + EPS);
  __bf16* obp = outb + (size_t)token * D;
  float ge[E];
#pragma unroll
  for (int e = 0; e < E; e++) ge[e] = 0.f;
#pragma unroll
  for (int j = 0; j < 4; j++) {
    int v4 = lane + j * 64;
    int d0 = v4 * 4;
    float4 gv = ((const float4*)g)[v4];
    float4 bv = ((const float4*)bta)[v4];
    float xv[4] = {x[j].x, x[j].y, x[j].z, x[j].w};
    float gg[4] = {gv.x, gv.y, gv.z, gv.w};
    float bb[4] = {bv.x, bv.y, bv.z, bv.w};
    bf16x4 o;
    const float4* sw4 = (const float4*)(selw + (size_t)d0 * E);
#pragma unroll
    for (int i = 0; i < 4; i++) {
      float y = (xv[i] - mean) * inv * gg[i] + bb[i];
      o[i] = (__bf16)y;
      float4 a = sw4[i * 2], b2 = sw4[i * 2 + 1];
      ge[0] += y * a.x;
      ge[1] += y * a.y;
      ge[2] += y * a.z;
      ge[3] += y * a.w;
      ge[4] += y * b2.x;
      ge[5] += y * b2.y;
      ge[6] += y * b2.z;
      ge[7] += y * b2.w;
    }
    *(bf16x4*)(obp + d0) = o;
  }
#pragma unroll
  for (int e = 0; e < E; e++) ge[e] = wave_reduce_sum(ge[e]);
  if (lane == 0) {
    float gg[E];
#pragma unroll
    for (int e = 0; e < E; e++) gg[e] = 1.f / (1.f + __expf(-ge[e]));
    int i0 = 0;
    for (int e = 1; e < E; e++)
      if (gg[e] > gg[i0]) i0 = e;
    int i1 = -1;
    for (int e = 0; e < E; e++) {
      if (e == i0) continue;
      if (i1 < 0 || gg[e] > gg[i1]) i1 = e;
    }
    float mm[E];
    for (int e = 0; e < E; e++) mm[e] = 0.f;
    mm[i0] = gg[i0];
    mm[i1] = gg[i1];
    for (int e = 0; e < E; e++) gm[(size_t)token * E + e] = mm[e];
  }
}

// ---------------- fp32 tiled GEMM (input projection, K=32) ----------
#define BM 64
#define BKT 16
__global__ __launch_bounds__(256) void gemm_kernel(
    const float* __restrict__ A, const float* __restrict__ Bw,
    const float* __restrict__ bias, float* __restrict__ C, int M, int N,
    int Kd) {
  __shared__ float As[BKT][BM + 1];
  __shared__ float Bs[BKT][BM + 1];
  int bm = blockIdx.y * BM, bn = blockIdx.x * BM;
  int tid = threadIdx.x;
  int tx = tid & 15, ty = tid >> 4;
  float acc[4][4] = {};
  for (int k0 = 0; k0 < Kd; k0 += BKT) {
#pragma unroll
    for (int j = 0; j < 4; j++) {
      int i = tid + j * 256;
      int r = i >> 4, c = i & 15;
      As[c][r] = A[(size_t)(bm + r) * Kd + k0 + c];
    }
#pragma unroll
    for (int j = 0; j < 4; j++) {
      int i = tid + j * 256;
      int n = i >> 4, c = i & 15;
      Bs[c][n] = Bw[(size_t)(bn + n) * Kd + k0 + c];
    }
    __syncthreads();
#pragma unroll
    for (int kk = 0; kk < BKT; kk++) {
      float a[4], bb[4];
#pragma unroll
      for (int i2 = 0; i2 < 4; i2++) a[i2] = As[kk][ty * 4 + i2];
#pragma unroll
      for (int i2 = 0; i2 < 4; i2++) bb[i2] = Bs[kk][tx * 4 + i2];
#pragma unroll
      for (int i2 = 0; i2 < 4; i2++)
#pragma unroll
        for (int j2 = 0; j2 < 4; j2++) acc[i2][j2] += a[i2] * bb[j2];
    }
    __syncthreads();
  }
#pragma unroll
  for (int i2 = 0; i2 < 4; i2++) {
    int row = bm + ty * 4 + i2;
#pragma unroll
    for (int j2 = 0; j2 < 4; j2++) {
      int col = bn + tx * 4 + j2;
      C[(size_t)row * N + col] = acc[i2][j2] + bias[col];
    }
  }
}

// ------- bf16 MFMA GEMM, 64xBN, templated BK, dbuf, XOR swizzle ---------
template <int NI, int BKQ>
__global__ __launch_bounds__(256) void mfma_gemm(
    const __bf16* __restrict__ A, int lda, const __bf16* __restrict__ Bt,
    const float* __restrict__ bias, float* __restrict__ C,
    __bf16* __restrict__ Cbf, int ldc, __bf16* __restrict__ vT,
    const float* __restrict__ gateScale, int K, int accum, int relu,
    int rope) {
  constexpr int BN = NI * 32;
  constexpr int CH = BKQ / 8;    // k-chunks (16B) per row
  constexpr int KKN = BKQ / 32;  // MFMA k-steps per iter
  constexpr int A_ELE = 64 * BKQ;
  constexpr int B_ELE = BN * BKQ;
  constexpr int STAGE_ELEMS = 2 * A_ELE + 2 * B_ELE;
  constexpr int TRANS_ELEMS = 128 * 66;  // vT transpose tile (NI=4 only)
  constexpr int SMEM_ELEMS =
      (TRANS_ELEMS > STAGE_ELEMS) ? TRANS_ELEMS : STAGE_ELEMS;
  __shared__ __bf16 smem[SMEM_ELEMS];
  __bf16* Asb = smem;              // [2][64*BKQ]
  __bf16* Bsb = smem + 2 * A_ELE;  // [2][BN*BKQ]
  // ---- T1: XCD-aware chunked remap (row-major chunks; nwg % 8 == 0) ----
  int nwg = gridDim.x * gridDim.y;
  int bid = blockIdx.y * gridDim.x + blockIdx.x;
  int t = (bid & 7) * (nwg >> 3) + (bid >> 3);
  int bxx = t % gridDim.x, byy = t / gridDim.x;
  int bm = byy * 64, bn = bxx * BN;
  int tid = threadIdx.x, lane = tid & 63, wv = tid >> 6;
  int wr = wv >> 1, wc = wv & 1;
  int half = lane >> 4, mrow = lane & 15;
  const __bf16* Ab = A + (size_t)bm * lda;
  const __bf16* Bb = Bt + (size_t)bn * K;
  fx4 acc[2][NI] = {};

  int abase[2], bbase[NI];
#pragma unroll
  for (int i = 0; i < 2; i++) abase[i] = wr * 32 + i * 16 + mrow;
#pragma unroll
  for (int j = 0; j < NI; j++) bbase[j] = wc * (NI * 16) + j * 16 + mrow;

  auto stage = [&](int buf, int k0) {
#pragma unroll
    for (int it = 0; it < (64 * CH) / 256; it++) {
      int c = tid + it * 256;
      int row = c / CH, g = (c % CH) ^ (row & (CH - 1));
      __builtin_amdgcn_global_load_lds(
          (const __attribute__((address_space(1))) void*)(Ab +
                                                          (size_t)row * lda +
                                                          k0 + g * 8),
          (__attribute__((address_space(3))) void*)(&Asb[buf * A_ELE + c * 8]),
          16, 0, 0);
    }
#pragma unroll
    for (int it = 0; it < (BN * CH) / 256; it++) {
      int c = tid + it * 256;
      int row = c / CH, g = (c % CH) ^ (row & (CH - 1));
      __builtin_amdgcn_global_load_lds(
          (const __attribute__((address_space(1))) void*)(Bb + (size_t)row * K +
                                                          k0 + g * 8),
          (__attribute__((address_space(3))) void*)(&Bsb[buf * B_ELE + c * 8]),
          16, 0, 0);
    }
  };
  stage(0, 0);
  for (int k0 = 0; k0 < K; k0 += BKQ) {
    int cur = (k0 / BKQ) & 1;
    __syncthreads();
    if (k0 + BKQ < K) stage(cur ^ 1, k0 + BKQ);
    bf16x8 af[2][KKN], bfr[NI][KKN];
#pragma unroll
    for (int i = 0; i < 2; i++) {
      int r = abase[i];
#pragma unroll
      for (int kk = 0; kk < KKN; kk++)
        af[i][kk] = *(const bf16x8*)(&Asb[cur * A_ELE + r * BKQ +
                                          (((kk * 4 + half) ^ (r & (CH - 1)))
                                           << 3)]);
    }
#pragma unroll
    for (int j = 0; j < NI; j++) {
      int r = bbase[j];
#pragma unroll
      for (int kk = 0; kk < KKN; kk++)
        bfr[j][kk] = *(const bf16x8*)(&Bsb[cur * B_ELE + r * BKQ +
                                           (((kk * 4 + half) ^ (r & (CH - 1)))
                                            << 3)]);
    }
#pragma unroll
    for (int kk = 0; kk < KKN; kk++)
#pragma unroll
      for (int i = 0; i < 2; i++)
#pragma unroll
        for (int j = 0; j < NI; j++)
          acc[i][j] = __builtin_amdgcn_mfma_f32_16x16x32_bf16(
              af[i][kk], bfr[j][kk], acc[i][j], 0, 0, 0);
  }
  if (vT && bn >= 2048) {
    // LDS-staged transpose: tile [d_local 0..127][tok_local 0..63], pad 66.
    __syncthreads();  // all waves done reading staging LDS
    __bf16* tb = smem;
#pragma unroll
    for (int i = 0; i < 2; i++) {
      int tl0 = wr * 32 + i * 16 + half * 4;
#pragma unroll
      for (int j = 0; j < NI; j++) {
        int dl = wc * (NI * 16) + j * 16 + mrow;
        float bb = bias ? bias[bn + dl] : 0.f;
#pragma unroll
        for (int r = 0; r < 4; r++)
          tb[dl * 66 + tl0 + r] = (__bf16)(acc[i][j][r] + bb);
      }
    }
    __syncthreads();
    // write out: 128 d-rows x 64 tokens; 8 lanes x bf16x8 = 128B full line
#pragma unroll
    for (int it = 0; it < 4; it++) {
      int idx = tid + it * 256;
      int dl = idx >> 3, c8 = idx & 7;
      bf16x8 v = *(const bf16x8*)(tb + dl * 66 + c8 * 8);
      *(bf16x8*)(vT + (size_t)(bn - 2048 + dl) * TOK + bm + c8 * 8) = v;
    }
    return;
  }
#pragma unroll
  for (int i = 0; i < 2; i++) {
#pragma unroll
    for (int r = 0; r < 4; r++) {
      int row = bm + wr * 32 + i * 16 + half * 4 + r;
      float vv[NI];
#pragma unroll
      for (int j = 0; j < NI; j++) {
        int col = bn + wc * (NI * 16) + j * 16 + mrow;
        float val = acc[i][j][r];
        if (bias) val += bias[col];
        if (relu) val = fmaxf(val, 0.f);
        if (gateScale) val *= gateScale[(size_t)row * E + (col >> 8)];
        vv[j] = val;
      }
      if (rope && NI == 4) {
        int spos = row & (S - 1);
#pragma unroll
        for (int jj = 0; jj < 2; jj++) {
          int hd = jj * 16 + mrow;  // 0..31
          float invf = exp2f(hd * -0.4152410118609825f);
          float ang = (float)spos * invf;
          float sn, cs;
          __sincosf(ang, &sn, &cs);
          float a0 = vv[jj], a1 = vv[jj + 2];
          vv[jj] = a0 * cs - a1 * sn;
          vv[jj + 2] = a1 * cs + a0 * sn;
        }
      }
#pragma unroll
      for (int j = 0; j < NI; j++) {
        int col = bn + wc * (NI * 16) + j * 16 + mrow;
        size_t addr = (size_t)row * ldc + col;
        if (Cbf)
          Cbf[addr] = (__bf16)vv[j];
        else if (accum)
          C[addr] += vv[j];
        else
          C[addr] = vv[j];
      }
    }
  }
}

// ---- fused weight prep (vectorized): transposes + ow cvt + bias --------
// Block ranges identical to round 26:
// [0,9216): qkv  [9216,15360): w1  [15360,21504): w2
// [21504,22016): ow cvt  [22016,22052): bias concat
// Transpose tiles 32x32: read float4/thread, LDS pad-33 scalar staging
// (<=2-way banks), write bf16x4/thread.
#define PREP_BLOCKS 22052
__global__ __launch_bounds__(256) void prep_all(
    const float* __restrict__ qw, const float* __restrict__ kw,
    const float* __restrict__ vw, __bf16* __restrict__ qkvt,
    const float* __restrict__ w1, __bf16* __restrict__ w1t,
    const float* __restrict__ w2, __bf16* __restrict__ w2t,
    const float* __restrict__ ow, __bf16* __restrict__ owt,
    const float* __restrict__ qb, const float* __restrict__ kb,
    const float* __restrict__ vb, float* __restrict__ qkvbias) {
  __shared__ float t[32][33];
  int bid = blockIdx.x;
  int tid = threadIdx.x;
  // transpose-thread mapping (all three transpose segments):
  int trow = tid >> 3, tc4 = tid & 7;  // read: row 0..31, float4 col 0..7
  int wc = tid >> 3, we = tid & 7;     // write: out-row 0..31, bf16x4 0..7
  if (bid < 9216) {
    int z = bid >> 10, rem = bid & 1023;
    int by = rem >> 5, bx = rem & 31;
    int w = z / LNUM, l = z % LNUM;
    const float* src = (w == 0 ? qw : (w == 1 ? kw : vw)) + (size_t)l * D * D;
    __bf16* d = qkvt + (size_t)l * 3 * D * D + (size_t)w * D * D;
    int r0 = by * 32, c0 = bx * 32;
    float4 v = *(const float4*)(src + (size_t)(r0 + trow) * D + c0 + tc4 * 4);
    t[trow][tc4 * 4 + 0] = v.x;
    t[trow][tc4 * 4 + 1] = v.y;
    t[trow][tc4 * 4 + 2] = v.z;
    t[trow][tc4 * 4 + 3] = v.w;
    __syncthreads();
    bf16x4 o;
#pragma unroll
    for (int k = 0; k < 4; k++) o[k] = (__bf16)t[we * 4 + k][wc];
    *(bf16x4*)(d + (size_t)(c0 + wc) * D + r0 + we * 4) = o;
  } else if (bid < 15360) {
    int b2 = bid - 9216;
    int z = b2 >> 8, rem = b2 & 255;
    int by = rem >> 3, bx = rem & 7;  // r over D (32), c over EH (8)
    const float* src = w1 + (size_t)z * D * EH;
    __bf16* d = w1t + (size_t)z * EH * D;
    int r0 = by * 32, c0 = bx * 32;
    float4 v = *(const float4*)(src + (size_t)(r0 + trow) * EH + c0 + tc4 * 4);
    t[trow][tc4 * 4 + 0] = v.x;
    t[trow][tc4 * 4 + 1] = v.y;
    t[trow][tc4 * 4 + 2] = v.z;
    t[trow][tc4 * 4 + 3] = v.w;
    __syncthreads();
    bf16x4 o;
#pragma unroll
    for (int k = 0; k < 4; k++) o[k] = (__bf16)t[we * 4 + k][wc];
    *(bf16x4*)(d + (size_t)(c0 + wc) * D + r0 + we * 4) = o;
  } else if (bid < 21504) {
    int b2 = bid - 15360;
    int z = b2 >> 8, rem = b2 & 255;
    int by = rem >> 5, bx = rem & 31;  // r over EH (8), c over D (32)
    int l = z / E, e = z % E;
    const float* src = w2 + (size_t)z * EH * D;
    __bf16* d = w2t + (size_t)l * D * E * EH + (size_t)e * EH;
    int r0 = by * 32, c0 = bx * 32;
    float4 v = *(const float4*)(src + (size_t)(r0 + trow) * D + c0 + tc4 * 4);
    t[trow][tc4 * 4 + 0] = v.x;
    t[trow][tc4 * 4 + 1] = v.y;
    t[trow][tc4 * 4 + 2] = v.z;
    t[trow][tc4 * 4 + 3] = v.w;
    __syncthreads();
    bf16x4 o;
#pragma unroll
    for (int k = 0; k < 4; k++) o[k] = (__bf16)t[we * 4 + k][wc];
    *(bf16x4*)(d + (size_t)(c0 + wc) * (E * EH) + r0 + we * 4) = o;
  } else if (bid < 22016) {
    int b2 = bid - 21504;
    int n4 = LNUM * D * D / 4;
    for (int i = b2 * 256 + tid; i < n4; i += 512 * 256) {
      float4 v = ((const float4*)ow)[i];
      bf16x4 o;
      o[0] = (__bf16)v.x;
      o[1] = (__bf16)v.y;
      o[2] = (__bf16)v.z;
      o[3] = (__bf16)v.w;
      ((bf16x4*)owt)[i] = o;
    }
  } else {
    int b2 = bid - 22016;
    int i = b2 * 256 + tid;
    if (i < LNUM * 3 * D) {
      int l = i / (3 * D), r = i % (3 * D);
      int w = r / D, dd = r % D;
      const float* src = w == 0 ? qb : (w == 1 ? kb : vb);
      qkvbias[i] = src[l * D + dd];
    }
  }
}

// ---------------- dbuf async-staged flash attention ----------------------
// Proven KVBLK=64 config: no-max softmax + deferred l-reduction; T1 remap.
#define P_LD 72
__global__ __launch_bounds__(256) void attn_dbuf(
    const __bf16* __restrict__ qk, const __bf16* __restrict__ vT,
    __bf16* __restrict__ obf) {
  __shared__ __bf16 Kt[2][64 * 64];    // 16 KB
  __shared__ __bf16 Vt[2][64 * 64];    // 16 KB
  __shared__ __bf16 Pb[4][16 * P_LD];  // 9 KB
  // ---- T1: XCD-aware chunked remap (nwg = 512, chunk = 64 = 4 hb) ----
  int nwg = gridDim.x * gridDim.y;
  int bid = blockIdx.y * gridDim.x + blockIdx.x;
  int t = (bid & 7) * (nwg >> 3) + (bid >> 3);
  int hb = t / gridDim.y;
  int q0 = (t % gridDim.y) * 64;
  int hh = hb >> 1, b = hb & 1;
  int tid = threadIdx.x, lane = tid & 63, wv = tid >> 6;
  int col = lane & 15, half = lane >> 4;
  const float scale = 0.125f;  // HD^-0.5
  __bf16* P = &Pb[wv][0];

  const __bf16* qp = qk + (size_t)(b * S + q0 + wv * 16 + col) * 2048 + hh * HD;
  bf16x8 qf0 = *(const bf16x8*)(qp + half * 8);
  bf16x8 qf1 = *(const bf16x8*)(qp + 32 + half * 8);
  const __bf16* kbase = qk + (size_t)(b * S) * 2048 + 1024 + hh * HD;
  const __bf16* vbase = vT + (size_t)(hh * HD) * TOK + b * S;

  int srow = tid >> 3, sslot = tid & 7;
  int sg = sslot ^ (srow & 7);
  int srow2 = (tid + 256) >> 3, sslot2 = tid & 7;
  int sg2 = sslot2 ^ (srow2 & 7);

  auto stage = [&](int buf, int t0) {
    __builtin_amdgcn_global_load_lds(
        (const __attribute__((address_space(1))) void*)(kbase +
                                                        (size_t)(t0 + srow) *
                                                            2048 +
                                                        sg * 8),
        (__attribute__((address_space(3))) void*)(&Kt[buf][tid * 8]), 16, 0, 0);
    __builtin_amdgcn_global_load_lds(
        (const __attribute__((address_space(1))) void*)(kbase +
                                                        (size_t)(t0 + srow2) *
                                                            2048 +
                                                        sg2 * 8),
        (__attribute__((address_space(3))) void*)(&Kt[buf][(tid + 256) * 8]),
        16, 0, 0);
    __builtin_amdgcn_global_load_lds(
        (const __attribute__((address_space(1))) void*)(vbase +
                                                        (size_t)srow * TOK +
                                                        t0 + sg * 8),
        (__attribute__((address_space(3))) void*)(&Vt[buf][tid * 8]), 16, 0, 0);
    __builtin_amdgcn_global_load_lds(
        (const __attribute__((address_space(1))) void*)(vbase +
                                                        (size_t)srow2 * TOK +
                                                        t0 + sg2 * 8),
        (__attribute__((address_space(3))) void*)(&Vt[buf][(tid + 256) * 8]),
        16, 0, 0);
  };

  fx4 Oacc[4] = {};
  float lpart[4] = {0.f, 0.f, 0.f, 0.f};

  stage(0, 0);
  for (int t0 = 0; t0 < S; t0 += 64) {
    int cur = (t0 >> 6) & 1;
    __syncthreads();
    if (t0 + 64 < S) stage(cur ^ 1, t0 + 64);
    // S = Q @ K^T
    fx4 sacc[4] = {};
#pragma unroll
    for (int n = 0; n < 4; n++) {
      int rowk = n * 16 + col;
      const __bf16* kp = &Kt[cur][rowk * 64];
      bf16x8 b0 = *(const bf16x8*)(kp + ((half ^ (rowk & 7)) << 3));
      bf16x8 b1 = *(const bf16x8*)(kp + (((4 + half) ^ (rowk & 7)) << 3));
      sacc[n] =
          __builtin_amdgcn_mfma_f32_16x16x32_bf16(qf0, b0, sacc[n], 0, 0, 0);
      sacc[n] =
          __builtin_amdgcn_mfma_f32_16x16x32_bf16(qf1, b1, sacc[n], 0, 0, 0);
    }
    // no-max softmax numerator
#pragma unroll
    for (int r = 0; r < 4; r++) {
      int prow = (half * 4 + r) * P_LD;
#pragma unroll
      for (int n = 0; n < 4; n++) {
        float p = __expf(sacc[n][r] * scale);
        lpart[r] += p;
        P[prow + n * 16 + col] = (__bf16)p;
      }
    }
    // O += P @ V
#pragma unroll
    for (int k0 = 0; k0 < 2; k0++) {
      bf16x8 af = *(const bf16x8*)(P + col * P_LD + k0 * 32 + half * 8);
#pragma unroll
      for (int n = 0; n < 4; n++) {
        int rowd = n * 16 + col;
        int g = k0 * 4 + half;
        bf16x8 bv =
            *(const bf16x8*)(&Vt[cur][rowd * 64 + ((g ^ (rowd & 7)) << 3)]);
        Oacc[n] =
            __builtin_amdgcn_mfma_f32_16x16x32_bf16(af, bv, Oacc[n], 0, 0, 0);
      }
    }
  }
#pragma unroll
  for (int r = 0; r < 4; r++) {
    float l = lpart[r];
#pragma unroll
    for (int msk = 1; msk < 16; msk <<= 1) l += __shfl_xor(l, msk);
    float inv = 1.f / l;
    int row = q0 + wv * 16 + half * 4 + r;
    __bf16* op = obf + (size_t)(b * S + row) * D + hh * HD;
#pragma unroll
    for (int n = 0; n < 4; n++) op[n * 16 + col] = (__bf16)(Oacc[n][r] * inv);
  }
}

// ---------------- final head: last token only ----------------
__global__ __launch_bounds__(256) void final_kernel(
    const float* __restrict__ h, const float* __restrict__ tg,
    const float* __restrict__ tb, const float* __restrict__ dg,
    const float* __restrict__ db, const float* __restrict__ ow,
    const float* __restrict__ ob, float* __restrict__ out) {
  int b = blockIdx.x;
  int tid = threadIdx.x;
  __shared__ float scratch[4];
  __shared__ float yf[D];
  const float* p = h + ((size_t)(b * S + (S - 1))) * D;
  float x[4];
  float s = 0.f, sq = 0.f;
#pragma unroll
  for (int i = 0; i < 4; i++) {
    x[i] = p[tid + i * 256];
    s += x[i];
    sq += x[i] * x[i];
  }
  s = block_reduce_sum256(s, scratch);
  sq = block_reduce_sum256(sq, scratch);
  float mean = s * (1.f / D);
  float inv = rsqrtf(sq * (1.f / D) - mean * mean + EPS);
  float y[4];
  s = 0.f;
  sq = 0.f;
#pragma unroll
  for (int i = 0; i < 4; i++) {
    int d = tid + i * 256;
    y[i] = (x[i] - mean) * inv * tg[d] + tb[d];
    s += y[i];
    sq += y[i] * y[i];
  }
  s = block_reduce_sum256(s, scratch);
  sq = block_reduce_sum256(sq, scratch);
  float mean2 = s * (1.f / D);
  float inv2 = rsqrtf(sq * (1.f / D) - mean2 * mean2 + EPS);
#pragma unroll
  for (int i = 0; i < 4; i++) {
    int d = tid + i * 256;
    yf[d] = (y[i] - mean2) * inv2 * dg[d] + db[d];
  }
  __syncthreads();
  for (int oo = 0; oo < NOUT; oo++) {
    float part = 0.f;
    for (int d = tid; d < D; d += 256) part += yf[d] * ow[(size_t)oo * D + d];
    part = block_reduce_sum256(part, scratch);
    if (tid == 0) out[b * NOUT + oo] = part + ob[oo];
  }
}

extern "C" void kernel_launch(void* const* d_in, const int* in_sizes, int n_in,
                              void* d_out, int out_size, void* d_ws,
                              size_t ws_size, hipStream_t stream) {
  const float* x = (const float*)d_in[0];
  const float* ln1_g = (const float*)d_in[1];
  const float* ln1_b = (const float*)d_in[2];
  const float* qw = (const float*)d_in[3];
  const float* qb_ = (const float*)d_in[4];
  const float* kw = (const float*)d_in[5];
  const float* kb_ = (const float*)d_in[6];
  const float* vw = (const float*)d_in[7];
  const float* vb_ = (const float*)d_in[8];
  const float* ow = (const float*)d_in[9];
  const float* ob = (const float*)d_in[10];
  const float* ln2_g = (const float*)d_in[11];
  const float* ln2_b = (const float*)d_in[12];
  const float* selw = (const float*)d_in[13];
  const float* w1 = (const float*)d_in[14];
  const float* w2 = (const float*)d_in[15];
  const float* lntg = (const float*)d_in[16];
  const float* lntb = (const float*)d_in[17];
  const float* lndg = (const float*)d_in[18];
  const float* lndb = (const float*)d_in[19];
  const float* inw = (const float*)d_in[20];
  const float* inb = (const float*)d_in[21];
  const float* outw = (const float*)d_in[22];
  const float* outb = (const float*)d_in[23];
  float* out = (float*)d_out;

  // ---- workspace layout (~76 MB) ----
  float* h = (float*)d_ws;                          // TOK*D f32
  float* gm = h + (size_t)TOK * D;                  // TOK*E
  float* qkvbias = gm + (size_t)TOK * E;            // L*3*D
  __bf16* xnb = (__bf16*)(qkvbias + LNUM * 3 * D);  // TOK*D
  __bf16* qkbf = xnb + (size_t)TOK * D;             // TOK*2048 (q|k)
  __bf16* vTb = qkbf + (size_t)TOK * 2048;          // D*TOK (v transposed)
  __bf16* obf = vTb + (size_t)D * TOK;              // TOK*D
  __bf16* qkvt = obf + (size_t)TOK * D;             // L*3*D*D
  __bf16* owt = qkvt + (size_t)LNUM * 3 * D * D;    // L*D*D
  __bf16* w1t = owt + (size_t)LNUM * D * D;         // L*E*EH*D
  __bf16* w2t = w1t + (size_t)LNUM * E * EH * D;    // L*D*E*EH
  __bf16* midb = qkbf;  // alias: q|k dead after attn; [TOK][2048]

  // ---- weight prep: ONE launch (vectorized) ----
  prep_all<<<PREP_BLOCKS, 256, 0, stream>>>(qw, kw, vw, qkvt, w1, w1t, w2, w2t,
                                            ow, owt, qb_, kb_, vb_, qkvbias);

  gemm_kernel<<<dim3(D / 64, TOK / 64), 256, 0, stream>>>(x, inw, inb, h, TOK,
                                                          D, DIN);
  for (int l = 0; l < LNUM; l++) {
    ln_bf_kernel<<<TOK / 4, 256, 0, stream>>>(h, ln1_g + l * D, ln1_b + l * D,
                                              xnb);
    // qkv folded: N=3072; q,k -> qkbf[token][2048] (+RoPE), v -> vT[d][token]
    mfma_gemm<4, 64><<<dim3(3072 / 128, TOK / 64), 256, 0, stream>>>(
        xnb, D, qkvt + (size_t)l * 3 * D * D, qkvbias + l * 3 * D, nullptr,
        qkbf, 2048, vTb, nullptr, D, 0, 0, 1);
    attn_dbuf<<<dim3(H * B, S / 64), 256, 0, stream>>>(qkbf, vTb, obf);
    // h += o @ ow^T + ob  (BK=128 -> 8 K-iters)
    mfma_gemm<2, 128><<<dim3(D / 64, TOK / 64), 256, 0, stream>>>(
        obf, D, owt + (size_t)l * D * D, ob + l * D, h, nullptr, D, nullptr,
        nullptr, D, 1, 0, 0);
    ln_gate_kernel<<<TOK / 4, 256, 0, stream>>>(h, ln2_g + l * D, ln2_b + l * D,
                                                selw + (size_t)l * D * E, xnb,
                                                gm);
    // w1 folded: mid[t][e*EH+eh] = relu(xn @ w1cat) * gate[t][e]
    mfma_gemm<4, 64><<<dim3(2048 / 128, TOK / 64), 256, 0, stream>>>(
        xnb, D, w1t + (size_t)l * E * EH * D, nullptr, nullptr, midb, 2048,
        nullptr, gm, D, 0, 1, 0);
    // h += mid @ w2stacked (K=2048, BK=128 -> 16 K-iters)
    mfma_gemm<2, 128><<<dim3(D / 64, TOK / 64), 256, 0, stream>>>(
        midb, 2048, w2t + (size_t)l * D * E * EH, nullptr, h, nullptr, D,
        nullptr, nullptr, 2048, 1, 0, 0);
  }
  final_kernel<<<B, 256, 0, stream>>>(h, lntg, lntb, lndg, lndb, outw, outb,
                                      out);
}

// Round 20
// 528.813 us; speedup vs baseline: 1.0340x; 1.0058x over previous
//
#include <hip/hip_runtime.h>

// MoEUT time-series decoder, round 28 = round-27 (531.9us) + full-line
// prep writes. Round-27 WIN overall but prep_all stayed ~41us @2.45 TB/s:
// its bf16x4 stores are 64B half-lines at 2KB stride (L2 merge hides the
// HBM amplification but the half-line stream caps BW). Fix: 64x32 tiles --
// each thread reads TWO float4 rows into t[64][33], writes ONE bf16x8;
// an 8-lane group = one full 128B line per output row. Same output
// layout/math; block ranges recomputed (11300 blocks). All other kernels
// byte-identical to round 27.

#define LNUM 3
#define D 1024
#define H 16
#define HD 64
#define E 8
#define EH 256
#define B 2
#define S 1024
#define DIN 32
#define NOUT 8
#define EPS 1e-5f
#define TOK (B * S)

typedef __bf16 bf16x8 __attribute__((ext_vector_type(8)));
typedef __bf16 bf16x4 __attribute__((ext_vector_type(4)));
typedef float fx4 __attribute__((ext_vector_type(4)));

// ---------------- reductions ----------------
__device__ inline float block_reduce_sum256(float v, float* scratch) {
  int lane = threadIdx.x & 63, wv = threadIdx.x >> 6;
#pragma unroll
  for (int off = 32; off; off >>= 1) v += __shfl_down(v, off);
  __syncthreads();
  if (lane == 0) scratch[wv] = v;
  __syncthreads();
  return scratch[0] + scratch[1] + scratch[2] + scratch[3];
}

__device__ inline float wave_reduce_sum(float v) {
#pragma unroll
  for (int msk = 1; msk < 64; msk <<= 1) v += __shfl_xor(v, msk);
  return v;
}

// ------ LayerNorm -> bf16 (wave-per-token, barrier-free) -----------------
__global__ __launch_bounds__(256) void ln_bf_kernel(
    const float* __restrict__ in, const float* __restrict__ g,
    const float* __restrict__ bta, __bf16* __restrict__ outb) {
  int lane = threadIdx.x & 63, wv = threadIdx.x >> 6;
  int token = blockIdx.x * 4 + wv;
  const float* p = in + (size_t)token * D;
  float4 x[4];
  float s = 0.f, sq = 0.f;
#pragma unroll
  for (int j = 0; j < 4; j++) {
    x[j] = ((const float4*)p)[lane + j * 64];
    s += x[j].x + x[j].y + x[j].z + x[j].w;
    sq += x[j].x * x[j].x + x[j].y * x[j].y + x[j].z * x[j].z +
          x[j].w * x[j].w;
  }
  s = wave_reduce_sum(s);
  sq = wave_reduce_sum(sq);
  float mean = s * (1.f / D);
  float inv = rsqrtf(sq * (1.f / D) - mean * mean + EPS);
  __bf16* obp = outb + (size_t)token * D;
#pragma unroll
  for (int j = 0; j < 4; j++) {
    int d0 = (lane + j * 64) * 4;
    float4 gv = ((const float4*)g)[lane + j * 64];
    float4 bv = ((const float4*)bta)[lane + j * 64];
    float xv[4] = {x[j].x, x[j].y, x[j].z, x[j].w};
    float gg[4] = {gv.x, gv.y, gv.z, gv.w};
    float bb[4] = {bv.x, bv.y, bv.z, bv.w};
    bf16x4 o;
#pragma unroll
    for (int i = 0; i < 4; i++)
      o[i] = (__bf16)((xv[i] - mean) * inv * gg[i] + bb[i]);
    *(bf16x4*)(obp + d0) = o;
  }
}

// ---- LayerNorm + sigmoid gate top-2 (wave-per-token, barrier-free) -----
__global__ __launch_bounds__(256) void ln_gate_kernel(
    const float* __restrict__ in, const float* __restrict__ g,
    const float* __restrict__ bta, const float* __restrict__ selw,
    __bf16* __restrict__ outb, float* __restrict__ gm) {
  int lane = threadIdx.x & 63, wv = threadIdx.x >> 6;
  int token = blockIdx.x * 4 + wv;
  const float* p = in + (size_t)token * D;
  float4 x[4];
  float s = 0.f, sq = 0.f;
#pragma unroll
  for (int j = 0; j < 4; j++) {
    x[j] = ((const float4*)p)[lane + j * 64];
    s += x[j].x + x[j].y + x[j].z + x[j].w;
    sq += x[j].x * x[j].x + x[j].y * x[j].y + x[j].z * x[j].z +
          x[j].w * x[j].w;
  }
  s = wave_reduce_sum(s);
  sq = wave_reduce_sum(sq);
  float mean = s * (1.f / D);
  float inv = rsqrtf(sq * (1.f / D) - mean * mean + EPS);
  __bf16* obp = outb + (size_t)token * D;
  float ge[E];
#pragma unroll
  for (int e = 0; e < E; e++) ge[e] = 0.f;
#pragma unroll
  for (int j = 0; j < 4; j++) {
    int v4 = lane + j * 64;
    int d0 = v4 * 4;
    float4 gv = ((const float4*)g)[v4];
    float4 bv = ((const float4*)bta)[v4];
    float xv[4] = {x[j].x, x[j].y, x[j].z, x[j].w};
    float gg[4] = {gv.x, gv.y, gv.z, gv.w};
    float bb[4] = {bv.x, bv.y, bv.z, bv.w};
    bf16x4 o;
    const float4* sw4 = (const float4*)(selw + (size_t)d0 * E);
#pragma unroll
    for (int i = 0; i < 4; i++) {
      float y = (xv[i] - mean) * inv * gg[i] + bb[i];
      o[i] = (__bf16)y;
      float4 a = sw4[i * 2], b2 = sw4[i * 2 + 1];
      ge[0] += y * a.x;
      ge[1] += y * a.y;
      ge[2] += y * a.z;
      ge[3] += y * a.w;
      ge[4] += y * b2.x;
      ge[5] += y * b2.y;
      ge[6] += y * b2.z;
      ge[7] += y * b2.w;
    }
    *(bf16x4*)(obp + d0) = o;
  }
#pragma unroll
  for (int e = 0; e < E; e++) ge[e] = wave_reduce_sum(ge[e]);
  if (lane == 0) {
    float gg[E];
#pragma unroll
    for (int e = 0; e < E; e++) gg[e] = 1.f / (1.f + __expf(-ge[e]));
    int i0 = 0;
    for (int e = 1; e < E; e++)
      if (gg[e] > gg[i0]) i0 = e;
    int i1 = -1;
    for (int e = 0; e < E; e++) {
      if (e == i0) continue;
      if (i1 < 0 || gg[e] > gg[i1]) i1 = e;
    }
    float mm[E];
    for (int e = 0; e < E; e++) mm[e] = 0.f;
    mm[i0] = gg[i0];
    mm[i1] = gg[i1];
    for (int e = 0; e < E; e++) gm[(size_t)token * E + e] = mm[e];
  }
}

// ---------------- fp32 tiled GEMM (input projection, K=32) ----------
#define BM 64
#define BKT 16
__global__ __launch_bounds__(256) void gemm_kernel(
    const float* __restrict__ A, const float* __restrict__ Bw,
    const float* __restrict__ bias, float* __restrict__ C, int M, int N,
    int Kd) {
  __shared__ float As[BKT][BM + 1];
  __shared__ float Bs[BKT][BM + 1];
  int bm = blockIdx.y * BM, bn = blockIdx.x * BM;
  int tid = threadIdx.x;
  int tx = tid & 15, ty = tid >> 4;
  float acc[4][4] = {};
  for (int k0 = 0; k0 < Kd; k0 += BKT) {
#pragma unroll
    for (int j = 0; j < 4; j++) {
      int i = tid + j * 256;
      int r = i >> 4, c = i & 15;
      As[c][r] = A[(size_t)(bm + r) * Kd + k0 + c];
    }
#pragma unroll
    for (int j = 0; j < 4; j++) {
      int i = tid + j * 256;
      int n = i >> 4, c = i & 15;
      Bs[c][n] = Bw[(size_t)(bn + n) * Kd + k0 + c];
    }
    __syncthreads();
#pragma unroll
    for (int kk = 0; kk < BKT; kk++) {
      float a[4], bb[4];
#pragma unroll
      for (int i2 = 0; i2 < 4; i2++) a[i2] = As[kk][ty * 4 + i2];
#pragma unroll
      for (int i2 = 0; i2 < 4; i2++) bb[i2] = Bs[kk][tx * 4 + i2];
#pragma unroll
      for (int i2 = 0; i2 < 4; i2++)
#pragma unroll
        for (int j2 = 0; j2 < 4; j2++) acc[i2][j2] += a[i2] * bb[j2];
    }
    __syncthreads();
  }
#pragma unroll
  for (int i2 = 0; i2 < 4; i2++) {
    int row = bm + ty * 4 + i2;
#pragma unroll
    for (int j2 = 0; j2 < 4; j2++) {
      int col = bn + tx * 4 + j2;
      C[(size_t)row * N + col] = acc[i2][j2] + bias[col];
    }
  }
}

// ------- bf16 MFMA GEMM, 64xBN, templated BK, dbuf, XOR swizzle ---------
template <int NI, int BKQ>
__global__ __launch_bounds__(256) void mfma_gemm(
    const __bf16* __restrict__ A, int lda, const __bf16* __restrict__ Bt,
    const float* __restrict__ bias, float* __restrict__ C,
    __bf16* __restrict__ Cbf, int ldc, __bf16* __restrict__ vT,
    const float* __restrict__ gateScale, int K, int accum, int relu,
    int rope) {
  constexpr int BN = NI * 32;
  constexpr int CH = BKQ / 8;    // k-chunks (16B) per row
  constexpr int KKN = BKQ / 32;  // MFMA k-steps per iter
  constexpr int A_ELE = 64 * BKQ;
  constexpr int B_ELE = BN * BKQ;
  constexpr int STAGE_ELEMS = 2 * A_ELE + 2 * B_ELE;
  constexpr int TRANS_ELEMS = 128 * 66;  // vT transpose tile (NI=4 only)
  constexpr int SMEM_ELEMS =
      (TRANS_ELEMS > STAGE_ELEMS) ? TRANS_ELEMS : STAGE_ELEMS;
  __shared__ __bf16 smem[SMEM_ELEMS];
  __bf16* Asb = smem;              // [2][64*BKQ]
  __bf16* Bsb = smem + 2 * A_ELE;  // [2][BN*BKQ]
  // ---- T1: XCD-aware chunked remap (row-major chunks; nwg % 8 == 0) ----
  int nwg = gridDim.x * gridDim.y;
  int bid = blockIdx.y * gridDim.x + blockIdx.x;
  int t = (bid & 7) * (nwg >> 3) + (bid >> 3);
  int bxx = t % gridDim.x, byy = t / gridDim.x;
  int bm = byy * 64, bn = bxx * BN;
  int tid = threadIdx.x, lane = tid & 63, wv = tid >> 6;
  int wr = wv >> 1, wc = wv & 1;
  int half = lane >> 4, mrow = lane & 15;
  const __bf16* Ab = A + (size_t)bm * lda;
  const __bf16* Bb = Bt + (size_t)bn * K;
  fx4 acc[2][NI] = {};

  int abase[2], bbase[NI];
#pragma unroll
  for (int i = 0; i < 2; i++) abase[i] = wr * 32 + i * 16 + mrow;
#pragma unroll
  for (int j = 0; j < NI; j++) bbase[j] = wc * (NI * 16) + j * 16 + mrow;

  auto stage = [&](int buf, int k0) {
#pragma unroll
    for (int it = 0; it < (64 * CH) / 256; it++) {
      int c = tid + it * 256;
      int row = c / CH, g = (c % CH) ^ (row & (CH - 1));
      __builtin_amdgcn_global_load_lds(
          (const __attribute__((address_space(1))) void*)(Ab +
                                                          (size_t)row * lda +
                                                          k0 + g * 8),
          (__attribute__((address_space(3))) void*)(&Asb[buf * A_ELE + c * 8]),
          16, 0, 0);
    }
#pragma unroll
    for (int it = 0; it < (BN * CH) / 256; it++) {
      int c = tid + it * 256;
      int row = c / CH, g = (c % CH) ^ (row & (CH - 1));
      __builtin_amdgcn_global_load_lds(
          (const __attribute__((address_space(1))) void*)(Bb + (size_t)row * K +
                                                          k0 + g * 8),
          (__attribute__((address_space(3))) void*)(&Bsb[buf * B_ELE + c * 8]),
          16, 0, 0);
    }
  };
  stage(0, 0);
  for (int k0 = 0; k0 < K; k0 += BKQ) {
    int cur = (k0 / BKQ) & 1;
    __syncthreads();
    if (k0 + BKQ < K) stage(cur ^ 1, k0 + BKQ);
    bf16x8 af[2][KKN], bfr[NI][KKN];
#pragma unroll
    for (int i = 0; i < 2; i++) {
      int r = abase[i];
#pragma unroll
      for (int kk = 0; kk < KKN; kk++)
        af[i][kk] = *(const bf16x8*)(&Asb[cur * A_ELE + r * BKQ +
                                          (((kk * 4 + half) ^ (r & (CH - 1)))
                                           << 3)]);
    }
#pragma unroll
    for (int j = 0; j < NI; j++) {
      int r = bbase[j];
#pragma unroll
      for (int kk = 0; kk < KKN; kk++)
        bfr[j][kk] = *(const bf16x8*)(&Bsb[cur * B_ELE + r * BKQ +
                                           (((kk * 4 + half) ^ (r & (CH - 1)))
                                            << 3)]);
    }
#pragma unroll
    for (int kk = 0; kk < KKN; kk++)
#pragma unroll
      for (int i = 0; i < 2; i++)
#pragma unroll
        for (int j = 0; j < NI; j++)
          acc[i][j] = __builtin_amdgcn_mfma_f32_16x16x32_bf16(
              af[i][kk], bfr[j][kk], acc[i][j], 0, 0, 0);
  }
  if (vT && bn >= 2048) {
    // LDS-staged transpose: tile [d_local 0..127][tok_local 0..63], pad 66.
    __syncthreads();  // all waves done reading staging LDS
    __bf16* tb = smem;
#pragma unroll
    for (int i = 0; i < 2; i++) {
      int tl0 = wr * 32 + i * 16 + half * 4;
#pragma unroll
      for (int j = 0; j < NI; j++) {
        int dl = wc * (NI * 16) + j * 16 + mrow;
        float bb = bias ? bias[bn + dl] : 0.f;
#pragma unroll
        for (int r = 0; r < 4; r++)
          tb[dl * 66 + tl0 + r] = (__bf16)(acc[i][j][r] + bb);
      }
    }
    __syncthreads();
    // write out: 128 d-rows x 64 tokens; 8 lanes x bf16x8 = 128B full line
#pragma unroll
    for (int it = 0; it < 4; it++) {
      int idx = tid + it * 256;
      int dl = idx >> 3, c8 = idx & 7;
      bf16x8 v = *(const bf16x8*)(tb + dl * 66 + c8 * 8);
      *(bf16x8*)(vT + (size_t)(bn - 2048 + dl) * TOK + bm + c8 * 8) = v;
    }
    return;
  }
#pragma unroll
  for (int i = 0; i < 2; i++) {
#pragma unroll
    for (int r = 0; r < 4; r++) {
      int row = bm + wr * 32 + i * 16 + half * 4 + r;
      float vv[NI];
#pragma unroll
      for (int j = 0; j < NI; j++) {
        int col = bn + wc * (NI * 16) + j * 16 + mrow;
        float val = acc[i][j][r];
        if (bias) val += bias[col];
        if (relu) val = fmaxf(val, 0.f);
        if (gateScale) val *= gateScale[(size_t)row * E + (col >> 8)];
        vv[j] = val;
      }
      if (rope && NI == 4) {
        int spos = row & (S - 1);
#pragma unroll
        for (int jj = 0; jj < 2; jj++) {
          int hd = jj * 16 + mrow;  // 0..31
          float invf = exp2f(hd * -0.4152410118609825f);
          float ang = (float)spos * invf;
          float sn, cs;
          __sincosf(ang, &sn, &cs);
          float a0 = vv[jj], a1 = vv[jj + 2];
          vv[jj] = a0 * cs - a1 * sn;
          vv[jj + 2] = a1 * cs + a0 * sn;
        }
      }
#pragma unroll
      for (int j = 0; j < NI; j++) {
        int col = bn + wc * (NI * 16) + j * 16 + mrow;
        size_t addr = (size_t)row * ldc + col;
        if (Cbf)
          Cbf[addr] = (__bf16)vv[j];
        else if (accum)
          C[addr] += vv[j];
        else
          C[addr] = vv[j];
      }
    }
  }
}

// ---- fused weight prep (full-line writes): 64x32 transpose tiles -------
// Block ranges:
// [0,4608): qkv  (z = w*LNUM+l; 16x32 tiles of 64r x 32c over DxD)
// [4608,7680): w1 (z = l*E+e; 16x8 tiles: 64r over D, 32c over EH)
// [7680,10752): w2 (z = l*E+e; 4x32 tiles: 64r over EH, 32c over D)
// [10752,11264): ow f32->bf16 cvt (512 blocks)
// [11264,11300): qkv bias concat (36 blocks)
// Read: 2x float4/thread; write: 1x bf16x8/thread (8 lanes = 128B line).
#define PREP_BLOCKS 11300
__global__ __launch_bounds__(256) void prep_all(
    const float* __restrict__ qw, const float* __restrict__ kw,
    const float* __restrict__ vw, __bf16* __restrict__ qkvt,
    const float* __restrict__ w1, __bf16* __restrict__ w1t,
    const float* __restrict__ w2, __bf16* __restrict__ w2t,
    const float* __restrict__ ow, __bf16* __restrict__ owt,
    const float* __restrict__ qb, const float* __restrict__ kb,
    const float* __restrict__ vb, float* __restrict__ qkvbias) {
  __shared__ float t[64][33];
  int bid = blockIdx.x;
  int tid = threadIdx.x;
  int trow = tid >> 3, tc4 = tid & 7;  // read: rows trow/trow+32, f4 col
  int wc = tid >> 3, we = tid & 7;     // write: out-row wc, bf16x8 we
  if (bid < 4608) {
    int z = bid >> 9, rem = bid & 511;
    int by = rem >> 5, bx = rem & 31;
    int w = z / LNUM, l = z % LNUM;
    const float* src = (w == 0 ? qw : (w == 1 ? kw : vw)) + (size_t)l * D * D;
    __bf16* d = qkvt + (size_t)l * 3 * D * D + (size_t)w * D * D;
    int r0 = by * 64, c0 = bx * 32;
#pragma unroll
    for (int h2 = 0; h2 < 2; h2++) {
      float4 v =
          *(const float4*)(src + (size_t)(r0 + trow + h2 * 32) * D + c0 +
                           tc4 * 4);
      t[trow + h2 * 32][tc4 * 4 + 0] = v.x;
      t[trow + h2 * 32][tc4 * 4 + 1] = v.y;
      t[trow + h2 * 32][tc4 * 4 + 2] = v.z;
      t[trow + h2 * 32][tc4 * 4 + 3] = v.w;
    }
    __syncthreads();
    bf16x8 o;
#pragma unroll
    for (int k = 0; k < 8; k++) o[k] = (__bf16)t[we * 8 + k][wc];
    *(bf16x8*)(d + (size_t)(c0 + wc) * D + r0 + we * 8) = o;
  } else if (bid < 7680) {
    int b2 = bid - 4608;
    int z = b2 >> 7, rem = b2 & 127;
    int by = rem >> 3, bx = rem & 7;  // 64r over D (16), 32c over EH (8)
    const float* src = w1 + (size_t)z * D * EH;
    __bf16* d = w1t + (size_t)z * EH * D;
    int r0 = by * 64, c0 = bx * 32;
#pragma unroll
    for (int h2 = 0; h2 < 2; h2++) {
      float4 v =
          *(const float4*)(src + (size_t)(r0 + trow + h2 * 32) * EH + c0 +
                           tc4 * 4);
      t[trow + h2 * 32][tc4 * 4 + 0] = v.x;
      t[trow + h2 * 32][tc4 * 4 + 1] = v.y;
      t[trow + h2 * 32][tc4 * 4 + 2] = v.z;
      t[trow + h2 * 32][tc4 * 4 + 3] = v.w;
    }
    __syncthreads();
    bf16x8 o;
#pragma unroll
    for (int k = 0; k < 8; k++) o[k] = (__bf16)t[we * 8 + k][wc];
    *(bf16x8*)(d + (size_t)(c0 + wc) * D + r0 + we * 8) = o;
  } else if (bid < 10752) {
    int b2 = bid - 7680;
    int z = b2 >> 7, rem = b2 & 127;
    int by = rem >> 5, bx = rem & 31;  // 64r over EH (4), 32c over D (32)
    int l = z / E, e = z % E;
    const float* src = w2 + (size_t)z * EH * D;
    __bf16* d = w2t + (size_t)l * D * E * EH + (size_t)e * EH;
    int r0 = by * 64, c0 = bx * 32;
#pragma unroll
    for (int h2 = 0; h2 < 2; h2++) {
      float4 v =
          *(const float4*)(src + (size_t)(r0 + trow + h2 * 32) * D + c0 +
                           tc4 * 4);
      t[trow + h2 * 32][tc4 * 4 + 0] = v.x;
      t[trow + h2 * 32][tc4 * 4 + 1] = v.y;
      t[trow + h2 * 32][tc4 * 4 + 2] = v.z;
      t[trow + h2 * 32][tc4 * 4 + 3] = v.w;
    }
    __syncthreads();
    bf16x8 o;
#pragma unroll
    for (int k = 0; k < 8; k++) o[k] = (__bf16)t[we * 8 + k][wc];
    *(bf16x8*)(d + (size_t)(c0 + wc) * (E * EH) + r0 + we * 8) = o;
  } else if (bid < 11264) {
    int b2 = bid - 10752;
    int n4 = LNUM * D * D / 4;
    for (int i = b2 * 256 + tid; i < n4; i += 512 * 256) {
      float4 v = ((const float4*)ow)[i];
      bf16x4 o;
      o[0] = (__bf16)v.x;
      o[1] = (__bf16)v.y;
      o[2] = (__bf16)v.z;
      o[3] = (__bf16)v.w;
      ((bf16x4*)owt)[i] = o;
    }
  } else {
    int b2 = bid - 11264;
    int i = b2 * 256 + tid;
    if (i < LNUM * 3 * D) {
      int l = i / (3 * D), r = i % (3 * D);
      int w = r / D, dd = r % D;
      const float* src = w == 0 ? qb : (w == 1 ? kb : vb);
      qkvbias[i] = src[l * D + dd];
    }
  }
}

// ---------------- dbuf async-staged flash attention ----------------------
// Proven KVBLK=64 config: no-max softmax + deferred l-reduction; T1 remap.
#define P_LD 72
__global__ __launch_bounds__(256) void attn_dbuf(
    const __bf16* __restrict__ qk, const __bf16* __restrict__ vT,
    __bf16* __restrict__ obf) {
  __shared__ __bf16 Kt[2][64 * 64];    // 16 KB
  __shared__ __bf16 Vt[2][64 * 64];    // 16 KB
  __shared__ __bf16 Pb[4][16 * P_LD];  // 9 KB
  // ---- T1: XCD-aware chunked remap (nwg = 512, chunk = 64 = 4 hb) ----
  int nwg = gridDim.x * gridDim.y;
  int bid = blockIdx.y * gridDim.x + blockIdx.x;
  int t = (bid & 7) * (nwg >> 3) + (bid >> 3);
  int hb = t / gridDim.y;
  int q0 = (t % gridDim.y) * 64;
  int hh = hb >> 1, b = hb & 1;
  int tid = threadIdx.x, lane = tid & 63, wv = tid >> 6;
  int col = lane & 15, half = lane >> 4;
  const float scale = 0.125f;  // HD^-0.5
  __bf16* P = &Pb[wv][0];

  const __bf16* qp = qk + (size_t)(b * S + q0 + wv * 16 + col) * 2048 + hh * HD;
  bf16x8 qf0 = *(const bf16x8*)(qp + half * 8);
  bf16x8 qf1 = *(const bf16x8*)(qp + 32 + half * 8);
  const __bf16* kbase = qk + (size_t)(b * S) * 2048 + 1024 + hh * HD;
  const __bf16* vbase = vT + (size_t)(hh * HD) * TOK + b * S;

  int srow = tid >> 3, sslot = tid & 7;
  int sg = sslot ^ (srow & 7);
  int srow2 = (tid + 256) >> 3, sslot2 = tid & 7;
  int sg2 = sslot2 ^ (srow2 & 7);

  auto stage = [&](int buf, int t0) {
    __builtin_amdgcn_global_load_lds(
        (const __attribute__((address_space(1))) void*)(kbase +
                                                        (size_t)(t0 + srow) *
                                                            2048 +
                                                        sg * 8),
        (__attribute__((address_space(3))) void*)(&Kt[buf][tid * 8]), 16, 0, 0);
    __builtin_amdgcn_global_load_lds(
        (const __attribute__((address_space(1))) void*)(kbase +
                                                        (size_t)(t0 + srow2) *
                                                            2048 +
                                                        sg2 * 8),
        (__attribute__((address_space(3))) void*)(&Kt[buf][(tid + 256) * 8]),
        16, 0, 0);
    __builtin_amdgcn_global_load_lds(
        (const __attribute__((address_space(1))) void*)(vbase +
                                                        (size_t)srow * TOK +
                                                        t0 + sg * 8),
        (__attribute__((address_space(3))) void*)(&Vt[buf][tid * 8]), 16, 0, 0);
    __builtin_amdgcn_global_load_lds(
        (const __attribute__((address_space(1))) void*)(vbase +
                                                        (size_t)srow2 * TOK +
                                                        t0 + sg2 * 8),
        (__attribute__((address_space(3))) void*)(&Vt[buf][(tid + 256) * 8]),
        16, 0, 0);
  };

  fx4 Oacc[4] = {};
  float lpart[4] = {0.f, 0.f, 0.f, 0.f};

  stage(0, 0);
  for (int t0 = 0; t0 < S; t0 += 64) {
    int cur = (t0 >> 6) & 1;
    __syncthreads();
    if (t0 + 64 < S) stage(cur ^ 1, t0 + 64);
    // S = Q @ K^T
    fx4 sacc[4] = {};
#pragma unroll
    for (int n = 0; n < 4; n++) {
      int rowk = n * 16 + col;
      const __bf16* kp = &Kt[cur][rowk * 64];
      bf16x8 b0 = *(const bf16x8*)(kp + ((half ^ (rowk & 7)) << 3));
      bf16x8 b1 = *(const bf16x8*)(kp + (((4 + half) ^ (rowk & 7)) << 3));
      sacc[n] =
          __builtin_amdgcn_mfma_f32_16x16x32_bf16(qf0, b0, sacc[n], 0, 0, 0);
      sacc[n] =
          __builtin_amdgcn_mfma_f32_16x16x32_bf16(qf1, b1, sacc[n], 0, 0, 0);
    }
    // no-max softmax numerator
#pragma unroll
    for (int r = 0; r < 4; r++) {
      int prow = (half * 4 + r) * P_LD;
#pragma unroll
      for (int n = 0; n < 4; n++) {
        float p = __expf(sacc[n][r] * scale);
        lpart[r] += p;
        P[prow + n * 16 + col] = (__bf16)p;
      }
    }
    // O += P @ V
#pragma unroll
    for (int k0 = 0; k0 < 2; k0++) {
      bf16x8 af = *(const bf16x8*)(P + col * P_LD + k0 * 32 + half * 8);
#pragma unroll
      for (int n = 0; n < 4; n++) {
        int rowd = n * 16 + col;
        int g = k0 * 4 + half;
        bf16x8 bv =
            *(const bf16x8*)(&Vt[cur][rowd * 64 + ((g ^ (rowd & 7)) << 3)]);
        Oacc[n] =
            __builtin_amdgcn_mfma_f32_16x16x32_bf16(af, bv, Oacc[n], 0, 0, 0);
      }
    }
  }
#pragma unroll
  for (int r = 0; r < 4; r++) {
    float l = lpart[r];
#pragma unroll
    for (int msk = 1; msk < 16; msk <<= 1) l += __shfl_xor(l, msk);
    float inv = 1.f / l;
    int row = q0 + wv * 16 + half * 4 + r;
    __bf16* op = obf + (size_t)(b * S + row) * D + hh * HD;
#pragma unroll
    for (int n = 0; n < 4; n++) op[n * 16 + col] = (__bf16)(Oacc[n][r] * inv);
  }
}

// ---------------- final head: last token only ----------------
__global__ __launch_bounds__(256) void final_kernel(
    const float* __restrict__ h, const float* __restrict__ tg,
    const float* __restrict__ tb, const float* __restrict__ dg,
    const float* __restrict__ db, const float* __restrict__ ow,
    const float* __restrict__ ob, float* __restrict__ out) {
  int b = blockIdx.x;
  int tid = threadIdx.x;
  __shared__ float scratch[4];
  __shared__ float yf[D];
  const float* p = h + ((size_t)(b * S + (S - 1))) * D;
  float x[4];
  float s = 0.f, sq = 0.f;
#pragma unroll
  for (int i = 0; i < 4; i++) {
    x[i] = p[tid + i * 256];
    s += x[i];
    sq += x[i] * x[i];
  }
  s = block_reduce_sum256(s, scratch);
  sq = block_reduce_sum256(sq, scratch);
  float mean = s * (1.f / D);
  float inv = rsqrtf(sq * (1.f / D) - mean * mean + EPS);
  float y[4];
  s = 0.f;
  sq = 0.f;
#pragma unroll
  for (int i = 0; i < 4; i++) {
    int d = tid + i * 256;
    y[i] = (x[i] - mean) * inv * tg[d] + tb[d];
    s += y[i];
    sq += y[i] * y[i];
  }
  s = block_reduce_sum256(s, scratch);
  sq = block_reduce_sum256(sq, scratch);
  float mean2 = s * (1.f / D);
  float inv2 = rsqrtf(sq * (1.f / D) - mean2 * mean2 + EPS);
#pragma unroll
  for (int i = 0; i < 4; i++) {
    int d = tid + i * 256;
    yf[d] = (y[i] - mean2) * inv2 * dg[d] + db[d];
  }
  __syncthreads();
  for (int oo = 0; oo < NOUT; oo++) {
    float part = 0.f;
    for (int d = tid; d < D; d += 256) part += yf[d] * ow[(size_t)oo * D + d];
    part = block_reduce_sum256(part, scratch);
    if (tid == 0) out[b * NOUT + oo] = part + ob[oo];
  }
}

extern "C" void kernel_launch(void* const* d_in, const int* in_sizes, int n_in,
                              void* d_out, int out_size, void* d_ws,
                              size_t ws_size, hipStream_t stream) {
  const float* x = (const float*)d_in[0];
  const float* ln1_g = (const float*)d_in[1];
  const float* ln1_b = (const float*)d_in[2];
  const float* qw = (const float*)d_in[3];
  const float* qb_ = (const float*)d_in[4];
  const float* kw = (const float*)d_in[5];
  const float* kb_ = (const float*)d_in[6];
  const float* vw = (const float*)d_in[7];
  const float* vb_ = (const float*)d_in[8];
  const float* ow = (const float*)d_in[9];
  const float* ob = (const float*)d_in[10];
  const float* ln2_g = (const float*)d_in[11];
  const float* ln2_b = (const float*)d_in[12];
  const float* selw = (const float*)d_in[13];
  const float* w1 = (const float*)d_in[14];
  const float* w2 = (const float*)d_in[15];
  const float* lntg = (const float*)d_in[16];
  const float* lntb = (const float*)d_in[17];
  const float* lndg = (const float*)d_in[18];
  const float* lndb = (const float*)d_in[19];
  const float* inw = (const float*)d_in[20];
  const float* inb = (const float*)d_in[21];
  const float* outw = (const float*)d_in[22];
  const float* outb = (const float*)d_in[23];
  float* out = (float*)d_out;

  // ---- workspace layout (~76 MB) ----
  float* h = (float*)d_ws;                          // TOK*D f32
  float* gm = h + (size_t)TOK * D;                  // TOK*E
  float* qkvbias = gm + (size_t)TOK * E;            // L*3*D
  __bf16* xnb = (__bf16*)(qkvbias + LNUM * 3 * D);  // TOK*D
  __bf16* qkbf = xnb + (size_t)TOK * D;             // TOK*2048 (q|k)
  __bf16* vTb = qkbf + (size_t)TOK * 2048;          // D*TOK (v transposed)
  __bf16* obf = vTb + (size_t)D * TOK;              // TOK*D
  __bf16* qkvt = obf + (size_t)TOK * D;             // L*3*D*D
  __bf16* owt = qkvt + (size_t)LNUM * 3 * D * D;    // L*D*D
  __bf16* w1t = owt + (size_t)LNUM * D * D;         // L*E*EH*D
  __bf16* w2t = w1t + (size_t)LNUM * E * EH * D;    // L*D*E*EH
  __bf16* midb = qkbf;  // alias: q|k dead after attn; [TOK][2048]

  // ---- weight prep: ONE launch (full-line writes) ----
  prep_all<<<PREP_BLOCKS, 256, 0, stream>>>(qw, kw, vw, qkvt, w1, w1t, w2, w2t,
                                            ow, owt, qb_, kb_, vb_, qkvbias);

  gemm_kernel<<<dim3(D / 64, TOK / 64), 256, 0, stream>>>(x, inw, inb, h, TOK,
                                                          D, DIN);
  for (int l = 0; l < LNUM; l++) {
    ln_bf_kernel<<<TOK / 4, 256, 0, stream>>>(h, ln1_g + l * D, ln1_b + l * D,
                                              xnb);
    // qkv folded: N=3072; q,k -> qkbf[token][2048] (+RoPE), v -> vT[d][token]
    mfma_gemm<4, 64><<<dim3(3072 / 128, TOK / 64), 256, 0, stream>>>(
        xnb, D, qkvt + (size_t)l * 3 * D * D, qkvbias + l * 3 * D, nullptr,
        qkbf, 2048, vTb, nullptr, D, 0, 0, 1);
    attn_dbuf<<<dim3(H * B, S / 64), 256, 0, stream>>>(qkbf, vTb, obf);
    // h += o @ ow^T + ob  (BK=128 -> 8 K-iters)
    mfma_gemm<2, 128><<<dim3(D / 64, TOK / 64), 256, 0, stream>>>(
        obf, D, owt + (size_t)l * D * D, ob + l * D, h, nullptr, D, nullptr,
        nullptr, D, 1, 0, 0);
    ln_gate_kernel<<<TOK / 4, 256, 0, stream>>>(h, ln2_g + l * D, ln2_b + l * D,
                                                selw + (size_t)l * D * E, xnb,
                                                gm);
    // w1 folded: mid[t][e*EH+eh] = relu(xn @ w1cat) * gate[t][e]
    mfma_gemm<4, 64><<<dim3(2048 / 128, TOK / 64), 256, 0, stream>>>(
        xnb, D, w1t + (size_t)l * E * EH * D, nullptr, nullptr, midb, 2048,
        nullptr, gm, D, 0, 1, 0);
    // h += mid @ w2stacked (K=2048, BK=128 -> 16 K-iters)
    mfma_gemm<2, 128><<<dim3(D / 64, TOK / 64), 256, 0, stream>>>(
        midb, 2048, w2t + (size_t)l * D * E * EH, nullptr, h, nullptr, D,
        nullptr, nullptr, 2048, 1, 0, 0);
  }
  final_kernel<<<B, 256, 0, stream>>>(h, lntg, lntb, lndg, lndb, outw, outb,
                                      out);
}